// Round 6
// baseline (663.367 us; speedup 1.0000x reference)
//
#include <hip/hip_runtime.h>
#include <math.h>

#define NN 20000
#define EE 320000
#define HID 64
#define EHID 32
#define HEADS 4

__device__ __forceinline__ float fast_tanh(float x) {
  float e = __expf(2.f * x);
  return 1.f - 2.f * __builtin_amdgcn_rcpf(e + 1.f);
}
__device__ __forceinline__ float fast_sigmoid(float x) {
  return __builtin_amdgcn_rcpf(1.f + __expf(-x));
}
__device__ __forceinline__ float bcast8(float v, int q) {
  // broadcast within 8-lane group: src lane = (lane & 0b11000) | q (BitMode swizzle)
  switch (q) {
    case 0: return __int_as_float(__builtin_amdgcn_ds_swizzle(__float_as_int(v), (0 << 5) | 0x18));
    case 1: return __int_as_float(__builtin_amdgcn_ds_swizzle(__float_as_int(v), (1 << 5) | 0x18));
    case 2: return __int_as_float(__builtin_amdgcn_ds_swizzle(__float_as_int(v), (2 << 5) | 0x18));
    case 3: return __int_as_float(__builtin_amdgcn_ds_swizzle(__float_as_int(v), (3 << 5) | 0x18));
    case 4: return __int_as_float(__builtin_amdgcn_ds_swizzle(__float_as_int(v), (4 << 5) | 0x18));
    case 5: return __int_as_float(__builtin_amdgcn_ds_swizzle(__float_as_int(v), (5 << 5) | 0x18));
    case 6: return __int_as_float(__builtin_amdgcn_ds_swizzle(__float_as_int(v), (6 << 5) | 0x18));
    default: return __int_as_float(__builtin_amdgcn_ds_swizzle(__float_as_int(v), (7 << 5) | 0x18));
  }
}

// ---------------------------------------------------------------------------
// Node encoder: Linear(9,32)+ReLU+Linear(32,64)+LayerNorm(64). Thread per node.
__global__ __launch_bounds__(256) void k_node_enc(
    const float* __restrict__ x, const float* __restrict__ w1, const float* __restrict__ b1,
    const float* __restrict__ w2, const float* __restrict__ b2,
    const float* __restrict__ g, const float* __restrict__ beta,
    float* __restrict__ h) {
  int n = blockIdx.x * blockDim.x + threadIdx.x;
  if (n >= NN) return;
  float xin[9];
#pragma unroll
  for (int k = 0; k < 9; k++) xin[k] = x[n * 9 + k];
  float hid[32];
#pragma unroll
  for (int j = 0; j < 32; j++) {
    float a = b1[j];
#pragma unroll
    for (int k = 0; k < 9; k++) a += xin[k] * w1[k * 32 + j];
    hid[j] = fmaxf(a, 0.f);
  }
  float o[64];
  float s = 0.f;
  for (int j = 0; j < 64; j++) {
    float a = b2[j];
#pragma unroll
    for (int k = 0; k < 32; k++) a += hid[k] * w2[k * 64 + j];
    o[j] = a;
    s += a;
  }
  float m = s * (1.f / 64.f);
  float v = 0.f;
  for (int j = 0; j < 64; j++) { float d = o[j] - m; v += d * d; }
  v *= (1.f / 64.f);
  float inv = rsqrtf(v + 1e-5f);
#pragma unroll
  for (int j4 = 0; j4 < 16; j4++) {
    float4 r;
    r.x = (o[j4 * 4 + 0] - m) * inv * g[j4 * 4 + 0] + beta[j4 * 4 + 0];
    r.y = (o[j4 * 4 + 1] - m) * inv * g[j4 * 4 + 1] + beta[j4 * 4 + 1];
    r.z = (o[j4 * 4 + 2] - m) * inv * g[j4 * 4 + 2] + beta[j4 * 4 + 2];
    r.w = (o[j4 * 4 + 3] - m) * inv * g[j4 * 4 + 3] + beta[j4 * 4 + 3];
    ((float4*)&h[n * 64])[j4] = r;
  }
}

// ---------------------------------------------------------------------------
// CSR histogram over col
__global__ __launch_bounds__(256) void k_hist(const int* __restrict__ ei, int* __restrict__ counts) {
  int e = blockIdx.x * 256 + threadIdx.x;
  if (e < EE) atomicAdd(&counts[ei[EE + e]], 1);
}
// shfl-based single-block scan: 1024 threads x 20 elements each.
__global__ __launch_bounds__(1024) void k_scan(
    const int* __restrict__ counts, int* __restrict__ rowptr, int* __restrict__ cursor) {
  __shared__ int wsum[16];
  int t = threadIdx.x, lane = t & 63, w = t >> 6;
  const int CH = 20;  // 1024*20 >= NN
  int base_i = t * CH;
  int local = 0;
  for (int i = 0; i < CH; i++) {
    int idx = base_i + i;
    if (idx < NN) local += counts[idx];
  }
  int v = local;
#pragma unroll
  for (int off = 1; off < 64; off <<= 1) {
    int u = __shfl_up(v, off);
    if (lane >= off) v += u;
  }
  if (lane == 63) wsum[w] = v;
  __syncthreads();
  int wbase = 0;
  for (int i = 0; i < w; i++) wbase += wsum[i];
  int run = wbase + v - local;  // exclusive prefix
  for (int i = 0; i < CH; i++) {
    int idx = base_i + i;
    if (idx < NN) {
      rowptr[idx] = run;
      cursor[idx] = run;
      run += counts[idx];
    }
  }
  if (t == 1023) rowptr[NN] = EE;
}

// ---------------------------------------------------------------------------
// Edge encoder, SORTED-output: computes ef/dev, grabs CSR slot via cursor, and
// writes efs/devs/rs directly in destination-node order. Thread per edge.
__global__ __launch_bounds__(256) void k_edge_enc(
    const float* __restrict__ ea, const float* __restrict__ w1, const float* __restrict__ b1,
    const float* __restrict__ w2, const float* __restrict__ b2,
    const float* __restrict__ g, const float* __restrict__ beta,
    const float* __restrict__ gat_wa, const int* __restrict__ ei,
    int* __restrict__ cursor,
    float* __restrict__ efs, float* __restrict__ devs, int* __restrict__ rs) {
  int e = blockIdx.x * blockDim.x + threadIdx.x;
  if (e >= EE) return;
  int row = ei[e], col = ei[EE + e];
  int pos = atomicAdd(&cursor[col], 1);
  float4 xin = ((const float4*)ea)[e];
  float hid[16];
#pragma unroll
  for (int j = 0; j < 16; j++) {
    float a = b1[j];
    a += xin.x * w1[0 * 16 + j];
    a += xin.y * w1[1 * 16 + j];
    a += xin.z * w1[2 * 16 + j];
    a += xin.w * w1[3 * 16 + j];
    hid[j] = fmaxf(a, 0.f);
  }
  float o[32];
  float s = 0.f;
#pragma unroll
  for (int j = 0; j < 32; j++) {
    float a = b2[j];
#pragma unroll
    for (int k = 0; k < 16; k++) a += hid[k] * w2[k * 32 + j];
    o[j] = a;
    s += a;
  }
  float m = s * (1.f / 32.f);
  float v = 0.f;
#pragma unroll
  for (int j = 0; j < 32; j++) { float d = o[j] - m; v += d * d; }
  v *= (1.f / 32.f);
  float inv = rsqrtf(v + 1e-5f);
  float d0 = 0.f, d1 = 0.f, d2 = 0.f;
  float vn[32];
#pragma unroll
  for (int j = 0; j < 32; j++) {
    vn[j] = (o[j] - m) * inv * g[j] + beta[j];
    d0 += vn[j] * gat_wa[0 * 160 + 128 + j];
    d1 += vn[j] * gat_wa[1 * 160 + 128 + j];
    d2 += vn[j] * gat_wa[2 * 160 + 128 + j];
  }
#pragma unroll
  for (int j4 = 0; j4 < 8; j4++) {
    float4 r;
    r.x = vn[j4 * 4 + 0]; r.y = vn[j4 * 4 + 1]; r.z = vn[j4 * 4 + 2]; r.w = vn[j4 * 4 + 3];
    ((float4*)&efs[(size_t)pos * 32])[j4] = r;
  }
  devs[0 * EE + pos] = d0;
  devs[1 * EE + pos] = d1;
  devs[2 * EE + pos] = d2;
  rs[pos] = row;
}

// ---------------------------------------------------------------------------
// Risk MLP part 1: hnode = h @ ra_w1[0:64,:] + b1. 16 nodes/block, transposed LDS.
__global__ __launch_bounds__(256) void k_risk_node(
    const float* __restrict__ h, const float* __restrict__ w1, const float* __restrict__ b1,
    float* __restrict__ hnode) {
  __shared__ float xsT[64][20];
  int t = threadIdx.x;
  int n0 = blockIdx.x * 16;
  const float4* h4 = (const float4*)h;
  {
    int m = t & 15, k4 = t >> 4;
    float4 xv = h4[(n0 + m) * 16 + k4];
    xsT[k4 * 4 + 0][m] = xv.x;
    xsT[k4 * 4 + 1][m] = xv.y;
    xsT[k4 * 4 + 2][m] = xv.z;
    xsT[k4 * 4 + 3][m] = xv.w;
  }
  __syncthreads();
  int j = t & 63, grp = t >> 6;
  float bv = b1[j];
  float a0 = bv, a1 = bv, a2 = bv, a3 = bv;
  for (int k = 0; k < 64; k++) {
    float wv = w1[k * 64 + j];
    float4 xv = *(const float4*)&xsT[k][grp * 4];
    a0 += xv.x * wv; a1 += xv.y * wv; a2 += xv.z * wv; a3 += xv.w * wv;
  }
  hnode[(n0 + grp * 4 + 0) * 64 + j] = a0;
  hnode[(n0 + grp * 4 + 1) * 64 + j] = a1;
  hnode[(n0 + grp * 4 + 2) * 64 + j] = a2;
  hnode[(n0 + grp * 4 + 3) * 64 + j] = a3;
}

// ---------------------------------------------------------------------------
// Risk MLP part 2, register-tiled (sorted domain): 8-lane group = 8 edges.
// Lane s holds edge (base+s)'s full ef row in VGPRs; per-k the group broadcasts
// ef[q][k] via ds_swizzle. Each lane computes cols s*8..s*8+7 for all 8 edges.
__global__ __launch_bounds__(256) void k_risk_edge(
    const float* __restrict__ hnode, const float* __restrict__ efs, const int* __restrict__ rs,
    const float* __restrict__ w1e, const float* __restrict__ w2, const float* __restrict__ b2_,
    float* __restrict__ rws) {
  int t = threadIdx.x, lane = t & 63;
  int s = lane & 7;
  int p = blockIdx.x * 256 + t;  // own sorted edge
  int myrow = rs[p];
  const float4* hnode4 = (const float4*)hnode;
  const float4* efs4 = (const float4*)efs;
  const float4* w1e4 = (const float4*)w1e;
  const float4* w24 = (const float4*)w2;
  // own edge's ef row -> 32 VGPRs
  float ev[32];
#pragma unroll
  for (int i = 0; i < 8; i++) {
    float4 tmp = efs4[(size_t)p * 8 + i];
    ev[i * 4 + 0] = tmp.x; ev[i * 4 + 1] = tmp.y; ev[i * 4 + 2] = tmp.z; ev[i * 4 + 3] = tmp.w;
  }
  // rows of the group's 8 edges
  int rowq[8];
#pragma unroll
  for (int q = 0; q < 8; q++)
    rowq[q] = __float_as_int(bcast8(__int_as_float(myrow), q));
  float acc[8][8];
#pragma unroll
  for (int q = 0; q < 8; q++) {
    float4 ha = hnode4[(size_t)rowq[q] * 16 + s * 2];
    float4 hb = hnode4[(size_t)rowq[q] * 16 + s * 2 + 1];
    acc[q][0] = ha.x; acc[q][1] = ha.y; acc[q][2] = ha.z; acc[q][3] = ha.w;
    acc[q][4] = hb.x; acc[q][5] = hb.y; acc[q][6] = hb.z; acc[q][7] = hb.w;
  }
#pragma unroll
  for (int k = 0; k < 32; k++) {
    float4 wa4 = w1e4[k * 16 + s * 2];
    float4 wb4 = w1e4[k * 16 + s * 2 + 1];
#pragma unroll
    for (int q = 0; q < 8; q++) {
      float ekq = bcast8(ev[k], q);
      acc[q][0] += ekq * wa4.x; acc[q][1] += ekq * wa4.y;
      acc[q][2] += ekq * wa4.z; acc[q][3] += ekq * wa4.w;
      acc[q][4] += ekq * wb4.x; acc[q][5] += ekq * wb4.y;
      acc[q][6] += ekq * wb4.z; acc[q][7] += ekq * wb4.w;
    }
  }
  float4 wva = w24[s * 2], wvb = w24[s * 2 + 1];
  float tq[8];
#pragma unroll
  for (int q = 0; q < 8; q++) {
    tq[q] = fast_tanh(acc[q][0]) * wva.x + fast_tanh(acc[q][1]) * wva.y +
            fast_tanh(acc[q][2]) * wva.z + fast_tanh(acc[q][3]) * wva.w +
            fast_tanh(acc[q][4]) * wvb.x + fast_tanh(acc[q][5]) * wvb.y +
            fast_tanh(acc[q][6]) * wvb.z + fast_tanh(acc[q][7]) * wvb.w;
  }
#pragma unroll
  for (int q = 0; q < 8; q++) {
    tq[q] += __shfl_xor(tq[q], 1);
    tq[q] += __shfl_xor(tq[q], 2);
    tq[q] += __shfl_xor(tq[q], 4);
  }
  float mine = tq[0];
  mine = (s == 1) ? tq[1] : mine;
  mine = (s == 2) ? tq[2] : mine;
  mine = (s == 3) ? tq[3] : mine;
  mine = (s == 4) ? tq[4] : mine;
  mine = (s == 5) ? tq[5] : mine;
  mine = (s == 6) ? tq[6] : mine;
  mine = (s == 7) ? tq[7] : mine;
  rws[p] = fast_sigmoid(mine + b2_[0]);
}

// ---------------------------------------------------------------------------
// Standalone xproj (layer 0): xproj = xh @ wl -> [N,256], fused di/dj.
__global__ __launch_bounds__(256) void k_xproj(
    const float* __restrict__ xh, const float* __restrict__ wl, const float* __restrict__ wa,
    float* __restrict__ xproj, float* __restrict__ di, float* __restrict__ dj) {
  __shared__ float xsT[64][20];
  int t = threadIdx.x, lane = t & 63, w = t >> 6;
  int n0 = blockIdx.x * 16;
  const float4* xh4 = (const float4*)xh;
  {
    int m = t & 15, k4 = t >> 4;
    float4 xv = xh4[(n0 + m) * 16 + k4];
    xsT[k4 * 4 + 0][m] = xv.x;
    xsT[k4 * 4 + 1][m] = xv.y;
    xsT[k4 * 4 + 2][m] = xv.z;
    xsT[k4 * 4 + 3][m] = xv.w;
  }
  __syncthreads();
  float acc[16];
#pragma unroll
  for (int m = 0; m < 16; m++) acc[m] = 0.f;
  for (int k = 0; k < 64; k++) {
    float wv = wl[k * 256 + t];
    float4 xa = *(const float4*)&xsT[k][0];
    float4 xb = *(const float4*)&xsT[k][4];
    float4 xc = *(const float4*)&xsT[k][8];
    float4 xd = *(const float4*)&xsT[k][12];
    acc[0] += xa.x * wv; acc[1] += xa.y * wv; acc[2] += xa.z * wv; acc[3] += xa.w * wv;
    acc[4] += xb.x * wv; acc[5] += xb.y * wv; acc[6] += xb.z * wv; acc[7] += xb.w * wv;
    acc[8] += xc.x * wv; acc[9] += xc.y * wv; acc[10] += xc.z * wv; acc[11] += xc.w * wv;
    acc[12] += xd.x * wv; acc[13] += xd.y * wv; acc[14] += xd.z * wv; acc[15] += xd.w * wv;
  }
  float wai = wa[lane], waj = wa[64 + lane];
#pragma unroll
  for (int m = 0; m < 16; m++) {
    xproj[(n0 + m) * 256 + t] = acc[m];
    float vi = acc[m] * wai;
    float vj = acc[m] * waj;
#pragma unroll
    for (int off = 32; off; off >>= 1) { vi += __shfl_xor(vi, off); vj += __shfl_xor(vj, off); }
    if (lane == 0) { di[(n0 + m) * 4 + w] = vi; dj[(n0 + m) * 4 + w] = vj; }
  }
}

// ---------------------------------------------------------------------------
// Fused alpha+exp+aggregation over the sorted edge stream. Wave per node,
// 2 edges in flight (half-wave slots). Outputs UNNORMALIZED sagg/tagg and
// atomically accumulates the global softmax denominator into gsum_l[4].
__global__ __launch_bounds__(256) void k_aggfused(
    const int* __restrict__ rowptr, const int* __restrict__ rs,
    const float* __restrict__ devl, const float* __restrict__ rws,
    const float* __restrict__ efs, const float* __restrict__ di,
    const float* __restrict__ dj,
    float* __restrict__ sagg, float* __restrict__ tagg, float* __restrict__ gsum_l) {
  __shared__ float bsum[4][4];
  int t = threadIdx.x, lane = t & 63, wv = t >> 6;
  int n = blockIdx.x * 4 + wv;
  int c = lane & 31, slot = lane >> 5;
  float4 djn = ((const float4*)dj)[n];
  float a0 = 0.f, a1 = 0.f, a2 = 0.f, a3 = 0.f;
  float s0 = 0.f, s1 = 0.f, s2 = 0.f, s3 = 0.f;
  int beg = rowptr[n], end = rowptr[n + 1];
  for (int i = beg + slot; i < end; i += 2) {
    int r = rs[i];
    float dev = devl[i];
    float rv = rws[i];
    float4 dr = ((const float4*)di)[r];
    float z0 = dr.x + djn.x + dev, z1 = dr.y + djn.y + dev;
    float z2 = dr.z + djn.z + dev, z3 = dr.w + djn.w + dev;
    z0 = ((z0 >= 0.f) ? z0 : 0.2f * z0) * rv;
    z1 = ((z1 >= 0.f) ? z1 : 0.2f * z1) * rv;
    z2 = ((z2 >= 0.f) ? z2 : 0.2f * z2) * rv;
    z3 = ((z3 >= 0.f) ? z3 : 0.2f * z3) * rv;
    float p0 = __expf(z0), p1 = __expf(z1), p2 = __expf(z2), p3 = __expf(z3);
    float ev = efs[(size_t)i * 32 + c];
    a0 += p0 * ev; a1 += p1 * ev; a2 += p2 * ev; a3 += p3 * ev;
    s0 += p0; s1 += p1; s2 += p2; s3 += p3;
  }
  a0 += __shfl_xor(a0, 32); a1 += __shfl_xor(a1, 32);
  a2 += __shfl_xor(a2, 32); a3 += __shfl_xor(a3, 32);
  s0 += __shfl_xor(s0, 32); s1 += __shfl_xor(s1, 32);
  s2 += __shfl_xor(s2, 32); s3 += __shfl_xor(s3, 32);
  if (slot == 0) {
    tagg[n * 128 + 0 * 32 + c] = a0;
    tagg[n * 128 + 1 * 32 + c] = a1;
    tagg[n * 128 + 2 * 32 + c] = a2;
    tagg[n * 128 + 3 * 32 + c] = a3;
    if (c < 4) {
      float sv = (c == 0) ? s0 : (c == 1) ? s1 : (c == 2) ? s2 : s3;
      sagg[n * 4 + c] = sv;
    }
  }
  if (lane == 0) { bsum[wv][0] = s0; bsum[wv][1] = s1; bsum[wv][2] = s2; bsum[wv][3] = s3; }
  __syncthreads();
  if (t < 4) atomicAdd(&gsum_l[t], bsum[0][t] + bsum[1][t] + bsum[2][t] + bsum[3][t]);
}

// ---------------------------------------------------------------------------
// Fused node update + next-layer xproj (+di/dj); applies 1/gsum normalization.
template <bool DO_XPROJ>
__global__ __launch_bounds__(256) void k_update_fused(
    const float* __restrict__ xproj, const float* __restrict__ sagg,
    const float* __restrict__ tagg, const float* __restrict__ gsum_l,
    const float* __restrict__ we, const float* __restrict__ wo, const float* __restrict__ wob,
    const float* __restrict__ wl_next, const float* __restrict__ wa_next,
    float* __restrict__ xh_out, float* __restrict__ xproj_out,
    float* __restrict__ di, float* __restrict__ dj) {
  __shared__ float tsT[128][20];
  __shared__ float usT[64][20];
  __shared__ float xhT[64][20];
  __shared__ float ss[16][4];
  int t = threadIdx.x, lane = t & 63, w = t >> 6;
  int n0 = blockIdx.x * 16;
  float4 gs = *((const float4*)gsum_l);
  float inv0 = 1.0f / gs.x, inv1 = 1.0f / gs.y, inv2 = 1.0f / gs.z, inv3 = 1.0f / gs.w;
  const float4* tagg4 = (const float4*)tagg;
  for (int i = t; i < 16 * 32; i += 256) {
    int m = i & 15, k4 = i >> 4;
    float invh = (k4 < 8) ? inv0 : (k4 < 16) ? inv1 : (k4 < 24) ? inv2 : inv3;
    float4 tv = tagg4[(n0 + m) * 32 + k4];
    tsT[k4 * 4 + 0][m] = tv.x * invh;
    tsT[k4 * 4 + 1][m] = tv.y * invh;
    tsT[k4 * 4 + 2][m] = tv.z * invh;
    tsT[k4 * 4 + 3][m] = tv.w * invh;
  }
  if (t < 64) {
    int hh = t & 3;
    float invh = (hh == 0) ? inv0 : (hh == 1) ? inv1 : (hh == 2) ? inv2 : inv3;
    ss[t >> 2][hh] = sagg[n0 * 4 + t] * invh;
  }
  __syncthreads();
  int j = lane, grp = w;
  float u0 = 0.f, u1 = 0.f, u2 = 0.f, u3 = 0.f;
#pragma unroll
  for (int h = 0; h < 4; h++) {
    u0 += xproj[(n0 + grp * 4 + 0) * 256 + h * 64 + j] * ss[grp * 4 + 0][h];
    u1 += xproj[(n0 + grp * 4 + 1) * 256 + h * 64 + j] * ss[grp * 4 + 1][h];
    u2 += xproj[(n0 + grp * 4 + 2) * 256 + h * 64 + j] * ss[grp * 4 + 2][h];
    u3 += xproj[(n0 + grp * 4 + 3) * 256 + h * 64 + j] * ss[grp * 4 + 3][h];
  }
  for (int hc = 0; hc < 128; hc++) {
    float wv = we[(hc & 31) * 256 + (hc >> 5) * 64 + j];
    float4 tv = *(const float4*)&tsT[hc][grp * 4];
    u0 += tv.x * wv; u1 += tv.y * wv; u2 += tv.z * wv; u3 += tv.w * wv;
  }
  *(float4*)&usT[j][grp * 4] = make_float4(u0 * 0.25f, u1 * 0.25f, u2 * 0.25f, u3 * 0.25f);
  __syncthreads();
  float ob = wob[j];
  float o0 = ob, o1 = ob, o2 = ob, o3 = ob;
  for (int k = 0; k < 64; k++) {
    float wv = wo[k * 64 + j];
    float4 uv = *(const float4*)&usT[k][grp * 4];
    o0 += uv.x * wv; o1 += uv.y * wv; o2 += uv.z * wv; o3 += uv.w * wv;
  }
  o0 = fmaxf(o0, 0.f); o1 = fmaxf(o1, 0.f); o2 = fmaxf(o2, 0.f); o3 = fmaxf(o3, 0.f);
  if (!DO_XPROJ) {
    xh_out[(n0 + grp * 4 + 0) * 64 + j] = o0;
    xh_out[(n0 + grp * 4 + 1) * 64 + j] = o1;
    xh_out[(n0 + grp * 4 + 2) * 64 + j] = o2;
    xh_out[(n0 + grp * 4 + 3) * 64 + j] = o3;
    return;
  }
  xhT[j][grp * 4 + 0] = o0;
  xhT[j][grp * 4 + 1] = o1;
  xhT[j][grp * 4 + 2] = o2;
  xhT[j][grp * 4 + 3] = o3;
  __syncthreads();
  float acc[16];
#pragma unroll
  for (int m = 0; m < 16; m++) acc[m] = 0.f;
  for (int k = 0; k < 64; k++) {
    float wv = wl_next[k * 256 + t];
    float4 xa = *(const float4*)&xhT[k][0];
    float4 xb = *(const float4*)&xhT[k][4];
    float4 xc = *(const float4*)&xhT[k][8];
    float4 xd = *(const float4*)&xhT[k][12];
    acc[0] += xa.x * wv; acc[1] += xa.y * wv; acc[2] += xa.z * wv; acc[3] += xa.w * wv;
    acc[4] += xb.x * wv; acc[5] += xb.y * wv; acc[6] += xb.z * wv; acc[7] += xb.w * wv;
    acc[8] += xc.x * wv; acc[9] += xc.y * wv; acc[10] += xc.z * wv; acc[11] += xc.w * wv;
    acc[12] += xd.x * wv; acc[13] += xd.y * wv; acc[14] += xd.z * wv; acc[15] += xd.w * wv;
  }
  float wai = wa_next[lane], waj = wa_next[64 + lane];
#pragma unroll
  for (int m = 0; m < 16; m++) {
    xproj_out[(n0 + m) * 256 + t] = acc[m];
    float vi = acc[m] * wai;
    float vj = acc[m] * waj;
#pragma unroll
    for (int off = 32; off; off >>= 1) { vi += __shfl_xor(vi, off); vj += __shfl_xor(vj, off); }
    if (lane == 0) { di[(n0 + m) * 4 + w] = vi; dj[(n0 + m) * 4 + w] = vj; }
  }
}

// ---------------------------------------------------------------------------
// Output layer: Linear(64,128)+ReLU+Linear(128,256)+LayerNorm(256). 8 nodes/block.
#define OPN 8
__global__ __launch_bounds__(256) void k_out(
    const float* __restrict__ xh, const float* __restrict__ w1, const float* __restrict__ b1,
    const float* __restrict__ w2, const float* __restrict__ b2,
    const float* __restrict__ g, const float* __restrict__ beta,
    float* __restrict__ out) {
  __shared__ float xsT[64][12];
  __shared__ float hsT[128][12];
  __shared__ float wp[4], wq[4];
  int t = threadIdx.x, lane = t & 63, w = t >> 6;
  int n0 = blockIdx.x * OPN;
  const float4* xh4 = (const float4*)xh;
  if (t < 128) {
    int m = t >> 4, k4 = t & 15;
    float4 xv = xh4[(n0 + m) * 16 + k4];
    xsT[k4 * 4 + 0][m] = xv.x;
    xsT[k4 * 4 + 1][m] = xv.y;
    xsT[k4 * 4 + 2][m] = xv.z;
    xsT[k4 * 4 + 3][m] = xv.w;
  }
  __syncthreads();
  for (int i = t; i < OPN * 128; i += 256) {
    int m = i >> 7, jj = i & 127;
    float a = b1[jj];
#pragma unroll
    for (int k = 0; k < 64; k++) a += xsT[k][m] * w1[k * 128 + jj];
    hsT[jj][m] = fmaxf(a, 0.f);
  }
  __syncthreads();
  float o[OPN];
  float bb = b2[t];
#pragma unroll
  for (int m = 0; m < OPN; m++) o[m] = bb;
  for (int k = 0; k < 128; k++) {
    float wv = w2[k * 256 + t];
    float4 ha = *(const float4*)&hsT[k][0];
    float4 hb = *(const float4*)&hsT[k][4];
    o[0] += ha.x * wv; o[1] += ha.y * wv; o[2] += ha.z * wv; o[3] += ha.w * wv;
    o[4] += hb.x * wv; o[5] += hb.y * wv; o[6] += hb.z * wv; o[7] += hb.w * wv;
  }
  float gv = g[t], bv = beta[t];
#pragma unroll
  for (int m = 0; m < OPN; m++) {
    float v = o[m], vv = o[m] * o[m];
#pragma unroll
    for (int off = 32; off; off >>= 1) { v += __shfl_xor(v, off); vv += __shfl_xor(vv, off); }
    if (lane == 0) { wp[w] = v; wq[w] = vv; }
    __syncthreads();
    float mean = (wp[0] + wp[1] + wp[2] + wp[3]) * (1.f / 256.f);
    float ex2 = (wq[0] + wq[1] + wq[2] + wq[3]) * (1.f / 256.f);
    float var = ex2 - mean * mean;
    __syncthreads();
    out[(n0 + m) * 256 + t] = (o[m] - mean) * rsqrtf(var + 1e-5f) * gv + bv;
  }
}

// ---------------------------------------------------------------------------
extern "C" void kernel_launch(void* const* d_in, const int* in_sizes, int n_in,
                              void* d_out, int out_size, void* d_ws, size_t ws_size,
                              hipStream_t stream) {
  const float* x         = (const float*)d_in[0];
  const float* edge_attr = (const float*)d_in[1];
  const int*   ei        = (const int*)d_in[2];
  const float* ne_w1 = (const float*)d_in[3];
  const float* ne_b1 = (const float*)d_in[4];
  const float* ne_w2 = (const float*)d_in[5];
  const float* ne_b2 = (const float*)d_in[6];
  const float* ne_g  = (const float*)d_in[7];
  const float* ne_be = (const float*)d_in[8];
  const float* ee_w1 = (const float*)d_in[9];
  const float* ee_b1 = (const float*)d_in[10];
  const float* ee_w2 = (const float*)d_in[11];
  const float* ee_b2 = (const float*)d_in[12];
  const float* ee_g  = (const float*)d_in[13];
  const float* ee_be = (const float*)d_in[14];
  const float* ra_w1 = (const float*)d_in[15];
  const float* ra_b1 = (const float*)d_in[16];
  const float* ra_w2 = (const float*)d_in[17];
  const float* ra_b2 = (const float*)d_in[18];
  const float* gat_wl  = (const float*)d_in[19];
  const float* gat_wa  = (const float*)d_in[20];
  const float* gat_we  = (const float*)d_in[21];
  const float* gat_wo  = (const float*)d_in[22];
  const float* gat_wob = (const float*)d_in[23];
  const float* ow_1 = (const float*)d_in[24];
  const float* ob_1 = (const float*)d_in[25];
  const float* ow_2 = (const float*)d_in[26];
  const float* ob_2 = (const float*)d_in[27];
  const float* o_g  = (const float*)d_in[28];
  const float* o_be = (const float*)d_in[29];
  float* out = (float*)d_out;

  char* wsb = (char*)d_ws;
  size_t off = 0;
  auto af = [&](size_t elems) -> float* { float* p = (float*)(wsb + off); off += elems * sizeof(float); return p; };
  auto ai = [&](size_t elems) -> int*   { int*   p = (int*)(wsb + off);   off += elems * sizeof(int);   return p; };

  float* h      = af((size_t)NN * 64);
  float* xh2    = af((size_t)NN * 64);
  float* efs    = af((size_t)EE * 32);   // ef rows, SORTED by destination node
  float* devs   = af((size_t)3 * EE);    // planar per-layer dev, sorted
  float* rws    = af((size_t)EE);        // risk weights, sorted
  float* xprojA = af((size_t)NN * 256);
  float* xprojB = af((size_t)NN * 256);  // aliased as hnode before layer 1
  float* di     = af((size_t)NN * 4);
  float* dj     = af((size_t)NN * 4);
  float* sagg   = af((size_t)NN * 4);
  float* tagg   = af((size_t)NN * 128);
  float* gsum   = af(12);                // 3 layers x 4 heads softmax denominators
  int* rs     = ai(EE);                  // source row per sorted edge
  int* counts = ai(NN);
  int* rowptr = ai(NN + 1);
  int* cursor = ai(NN);
  float* hnode = xprojB;  // consumed by k_risk_edge before xprojB's first write
  (void)ws_size; (void)n_in; (void)in_sizes; (void)out_size;

  hipMemsetAsync(counts, 0, NN * sizeof(int), stream);
  hipMemsetAsync(gsum, 0, 12 * sizeof(float), stream);
  k_hist<<<EE / 256, 256, 0, stream>>>(ei, counts);
  k_node_enc<<<(NN + 255) / 256, 256, 0, stream>>>(x, ne_w1, ne_b1, ne_w2, ne_b2, ne_g, ne_be, h);
  k_scan<<<1, 1024, 0, stream>>>(counts, rowptr, cursor);
  k_edge_enc<<<EE / 256, 256, 0, stream>>>(edge_attr, ee_w1, ee_b1, ee_w2, ee_b2, ee_g, ee_be,
                                           gat_wa, ei, cursor, efs, devs, rs);
  k_risk_node<<<NN / 16, 256, 0, stream>>>(h, ra_w1, ra_b1, hnode);
  k_risk_edge<<<EE / 256, 256, 0, stream>>>(hnode, efs, rs, ra_w1 + 64 * 64, ra_w2, ra_b2, rws);
  k_xproj<<<NN / 16, 256, 0, stream>>>(h, gat_wl, gat_wa, xprojA, di, dj);

  float* xp_cur = xprojA;
  float* xp_nxt = xprojB;
  for (int l = 0; l < 3; l++) {
    const float* we  = gat_we + (size_t)l * 32 * 256;
    const float* wo  = gat_wo + (size_t)l * 64 * 64;
    const float* wob = gat_wob + (size_t)l * 64;
    float* gsum_l = gsum + l * 4;

    k_aggfused<<<NN / 4, 256, 0, stream>>>(rowptr, rs, devs + (size_t)l * EE, rws, efs,
                                           di, dj, sagg, tagg, gsum_l);
    if (l < 2) {
      const float* wl_n = gat_wl + (size_t)(l + 1) * 64 * 256;
      const float* wa_n = gat_wa + (size_t)(l + 1) * 160;
      k_update_fused<true><<<NN / 16, 256, 0, stream>>>(
          xp_cur, sagg, tagg, gsum_l, we, wo, wob, wl_n, wa_n, nullptr, xp_nxt, di, dj);
      float* tmp = xp_cur; xp_cur = xp_nxt; xp_nxt = tmp;
    } else {
      k_update_fused<false><<<NN / 16, 256, 0, stream>>>(
          xp_cur, sagg, tagg, gsum_l, we, wo, wob, nullptr, nullptr, xh2, nullptr, nullptr, nullptr);
    }
  }

  k_out<<<NN / OPN, 256, 0, stream>>>(xh2, ow_1, ob_1, ow_2, ob_2, o_g, o_be, out);
}

// Round 7
// 546.677 us; speedup vs baseline: 1.2135x; 1.2135x over previous
//
#include <hip/hip_runtime.h>
#include <math.h>

#define NN 20000
#define EE 320000
#define HID 64
#define EHID 32
#define HEADS 4

__device__ __forceinline__ float fast_tanh(float x) {
  float e = __expf(2.f * x);
  return 1.f - 2.f * __builtin_amdgcn_rcpf(e + 1.f);
}
__device__ __forceinline__ float fast_sigmoid(float x) {
  return __builtin_amdgcn_rcpf(1.f + __expf(-x));
}
__device__ __forceinline__ float bcast8(float v, int q) {
  // broadcast within 8-lane group: src lane = (lane & 0b11000) | q (BitMode swizzle)
  switch (q) {
    case 0: return __int_as_float(__builtin_amdgcn_ds_swizzle(__float_as_int(v), (0 << 5) | 0x18));
    case 1: return __int_as_float(__builtin_amdgcn_ds_swizzle(__float_as_int(v), (1 << 5) | 0x18));
    case 2: return __int_as_float(__builtin_amdgcn_ds_swizzle(__float_as_int(v), (2 << 5) | 0x18));
    case 3: return __int_as_float(__builtin_amdgcn_ds_swizzle(__float_as_int(v), (3 << 5) | 0x18));
    case 4: return __int_as_float(__builtin_amdgcn_ds_swizzle(__float_as_int(v), (4 << 5) | 0x18));
    case 5: return __int_as_float(__builtin_amdgcn_ds_swizzle(__float_as_int(v), (5 << 5) | 0x18));
    case 6: return __int_as_float(__builtin_amdgcn_ds_swizzle(__float_as_int(v), (6 << 5) | 0x18));
    default: return __int_as_float(__builtin_amdgcn_ds_swizzle(__float_as_int(v), (7 << 5) | 0x18));
  }
}

// ---------------------------------------------------------------------------
// Node encoder: Linear(9,32)+ReLU+Linear(32,64)+LayerNorm(64). Thread per node.
__global__ __launch_bounds__(256) void k_node_enc(
    const float* __restrict__ x, const float* __restrict__ w1, const float* __restrict__ b1,
    const float* __restrict__ w2, const float* __restrict__ b2,
    const float* __restrict__ g, const float* __restrict__ beta,
    float* __restrict__ h) {
  int n = blockIdx.x * blockDim.x + threadIdx.x;
  if (n >= NN) return;
  float xin[9];
#pragma unroll
  for (int k = 0; k < 9; k++) xin[k] = x[n * 9 + k];
  float hid[32];
#pragma unroll
  for (int j = 0; j < 32; j++) {
    float a = b1[j];
#pragma unroll
    for (int k = 0; k < 9; k++) a += xin[k] * w1[k * 32 + j];
    hid[j] = fmaxf(a, 0.f);
  }
  float o[64];
  float s = 0.f;
  for (int j = 0; j < 64; j++) {
    float a = b2[j];
#pragma unroll
    for (int k = 0; k < 32; k++) a += hid[k] * w2[k * 64 + j];
    o[j] = a;
    s += a;
  }
  float m = s * (1.f / 64.f);
  float v = 0.f;
  for (int j = 0; j < 64; j++) { float d = o[j] - m; v += d * d; }
  v *= (1.f / 64.f);
  float inv = rsqrtf(v + 1e-5f);
#pragma unroll
  for (int j4 = 0; j4 < 16; j4++) {
    float4 r;
    r.x = (o[j4 * 4 + 0] - m) * inv * g[j4 * 4 + 0] + beta[j4 * 4 + 0];
    r.y = (o[j4 * 4 + 1] - m) * inv * g[j4 * 4 + 1] + beta[j4 * 4 + 1];
    r.z = (o[j4 * 4 + 2] - m) * inv * g[j4 * 4 + 2] + beta[j4 * 4 + 2];
    r.w = (o[j4 * 4 + 3] - m) * inv * g[j4 * 4 + 3] + beta[j4 * 4 + 3];
    ((float4*)&h[n * 64])[j4] = r;
  }
}

// ---------------------------------------------------------------------------
// CSR histogram over col
__global__ __launch_bounds__(256) void k_hist(const int* __restrict__ ei, int* __restrict__ counts) {
  int e = blockIdx.x * 256 + threadIdx.x;
  if (e < EE) atomicAdd(&counts[ei[EE + e]], 1);
}
// shfl-based single-block scan: 1024 threads x 20 elements each.
__global__ __launch_bounds__(1024) void k_scan(
    const int* __restrict__ counts, int* __restrict__ rowptr, int* __restrict__ cursor) {
  __shared__ int wsum[16];
  int t = threadIdx.x, lane = t & 63, w = t >> 6;
  const int CH = 20;  // 1024*20 >= NN
  int base_i = t * CH;
  int local = 0;
  for (int i = 0; i < CH; i++) {
    int idx = base_i + i;
    if (idx < NN) local += counts[idx];
  }
  int v = local;
#pragma unroll
  for (int off = 1; off < 64; off <<= 1) {
    int u = __shfl_up(v, off);
    if (lane >= off) v += u;
  }
  if (lane == 63) wsum[w] = v;
  __syncthreads();
  int wbase = 0;
  for (int i = 0; i < w; i++) wbase += wsum[i];
  int run = wbase + v - local;  // exclusive prefix
  for (int i = 0; i < CH; i++) {
    int idx = base_i + i;
    if (idx < NN) {
      rowptr[idx] = run;
      cursor[idx] = run;
      run += counts[idx];
    }
  }
  if (t == 1023) rowptr[NN] = EE;
}

// ---------------------------------------------------------------------------
// Edge encoder, SORTED-output: computes ef/dev, grabs CSR slot via cursor, and
// writes efs/devs4/rcs in destination-node order. Thread per edge.
__global__ __launch_bounds__(256) void k_edge_enc(
    const float* __restrict__ ea, const float* __restrict__ w1, const float* __restrict__ b1,
    const float* __restrict__ w2, const float* __restrict__ b2,
    const float* __restrict__ g, const float* __restrict__ beta,
    const float* __restrict__ gat_wa, const int* __restrict__ ei,
    int* __restrict__ cursor,
    float* __restrict__ efs, float4* __restrict__ devs4, int2* __restrict__ rcs) {
  int e = blockIdx.x * blockDim.x + threadIdx.x;
  if (e >= EE) return;
  int row = ei[e], col = ei[EE + e];
  int pos = atomicAdd(&cursor[col], 1);
  float4 xin = ((const float4*)ea)[e];
  float hid[16];
#pragma unroll
  for (int j = 0; j < 16; j++) {
    float a = b1[j];
    a += xin.x * w1[0 * 16 + j];
    a += xin.y * w1[1 * 16 + j];
    a += xin.z * w1[2 * 16 + j];
    a += xin.w * w1[3 * 16 + j];
    hid[j] = fmaxf(a, 0.f);
  }
  float o[32];
  float s = 0.f;
#pragma unroll
  for (int j = 0; j < 32; j++) {
    float a = b2[j];
#pragma unroll
    for (int k = 0; k < 16; k++) a += hid[k] * w2[k * 32 + j];
    o[j] = a;
    s += a;
  }
  float m = s * (1.f / 32.f);
  float v = 0.f;
#pragma unroll
  for (int j = 0; j < 32; j++) { float d = o[j] - m; v += d * d; }
  v *= (1.f / 32.f);
  float inv = rsqrtf(v + 1e-5f);
  float d0 = 0.f, d1 = 0.f, d2 = 0.f;
  float vn[32];
#pragma unroll
  for (int j = 0; j < 32; j++) {
    vn[j] = (o[j] - m) * inv * g[j] + beta[j];
    d0 += vn[j] * gat_wa[0 * 160 + 128 + j];
    d1 += vn[j] * gat_wa[1 * 160 + 128 + j];
    d2 += vn[j] * gat_wa[2 * 160 + 128 + j];
  }
#pragma unroll
  for (int j4 = 0; j4 < 8; j4++) {
    float4 r;
    r.x = vn[j4 * 4 + 0]; r.y = vn[j4 * 4 + 1]; r.z = vn[j4 * 4 + 2]; r.w = vn[j4 * 4 + 3];
    ((float4*)&efs[(size_t)pos * 32])[j4] = r;
  }
  devs4[pos] = make_float4(d0, d1, d2, 0.f);
  rcs[pos] = make_int2(row, col);
}

// ---------------------------------------------------------------------------
// Risk MLP part 1: hnode = h @ ra_w1[0:64,:] + b1. 16 nodes/block, transposed LDS.
__global__ __launch_bounds__(256) void k_risk_node(
    const float* __restrict__ h, const float* __restrict__ w1, const float* __restrict__ b1,
    float* __restrict__ hnode) {
  __shared__ float xsT[64][20];
  int t = threadIdx.x;
  int n0 = blockIdx.x * 16;
  const float4* h4 = (const float4*)h;
  {
    int m = t & 15, k4 = t >> 4;
    float4 xv = h4[(n0 + m) * 16 + k4];
    xsT[k4 * 4 + 0][m] = xv.x;
    xsT[k4 * 4 + 1][m] = xv.y;
    xsT[k4 * 4 + 2][m] = xv.z;
    xsT[k4 * 4 + 3][m] = xv.w;
  }
  __syncthreads();
  int j = t & 63, grp = t >> 6;
  float bv = b1[j];
  float a0 = bv, a1 = bv, a2 = bv, a3 = bv;
  for (int k = 0; k < 64; k++) {
    float wv = w1[k * 64 + j];
    float4 xv = *(const float4*)&xsT[k][grp * 4];
    a0 += xv.x * wv; a1 += xv.y * wv; a2 += xv.z * wv; a3 += xv.w * wv;
  }
  hnode[(n0 + grp * 4 + 0) * 64 + j] = a0;
  hnode[(n0 + grp * 4 + 1) * 64 + j] = a1;
  hnode[(n0 + grp * 4 + 2) * 64 + j] = a2;
  hnode[(n0 + grp * 4 + 3) * 64 + j] = a3;
}

// ---------------------------------------------------------------------------
// Risk MLP part 2, register-tiled (sorted domain): 8-lane group = 8 edges.
__global__ __launch_bounds__(256) void k_risk_edge(
    const float* __restrict__ hnode, const float* __restrict__ efs, const int2* __restrict__ rcs,
    const float* __restrict__ w1e, const float* __restrict__ w2, const float* __restrict__ b2_,
    float* __restrict__ rws) {
  int t = threadIdx.x, lane = t & 63;
  int s = lane & 7;
  int p = blockIdx.x * 256 + t;  // own sorted edge
  int myrow = rcs[p].x;
  const float4* hnode4 = (const float4*)hnode;
  const float4* efs4 = (const float4*)efs;
  const float4* w1e4 = (const float4*)w1e;
  const float4* w24 = (const float4*)w2;
  float ev[32];
#pragma unroll
  for (int i = 0; i < 8; i++) {
    float4 tmp = efs4[(size_t)p * 8 + i];
    ev[i * 4 + 0] = tmp.x; ev[i * 4 + 1] = tmp.y; ev[i * 4 + 2] = tmp.z; ev[i * 4 + 3] = tmp.w;
  }
  int rowq[8];
#pragma unroll
  for (int q = 0; q < 8; q++)
    rowq[q] = __float_as_int(bcast8(__int_as_float(myrow), q));
  float acc[8][8];
#pragma unroll
  for (int q = 0; q < 8; q++) {
    float4 ha = hnode4[(size_t)rowq[q] * 16 + s * 2];
    float4 hb = hnode4[(size_t)rowq[q] * 16 + s * 2 + 1];
    acc[q][0] = ha.x; acc[q][1] = ha.y; acc[q][2] = ha.z; acc[q][3] = ha.w;
    acc[q][4] = hb.x; acc[q][5] = hb.y; acc[q][6] = hb.z; acc[q][7] = hb.w;
  }
#pragma unroll
  for (int k = 0; k < 32; k++) {
    float4 wa4 = w1e4[k * 16 + s * 2];
    float4 wb4 = w1e4[k * 16 + s * 2 + 1];
#pragma unroll
    for (int q = 0; q < 8; q++) {
      float ekq = bcast8(ev[k], q);
      acc[q][0] += ekq * wa4.x; acc[q][1] += ekq * wa4.y;
      acc[q][2] += ekq * wa4.z; acc[q][3] += ekq * wa4.w;
      acc[q][4] += ekq * wb4.x; acc[q][5] += ekq * wb4.y;
      acc[q][6] += ekq * wb4.z; acc[q][7] += ekq * wb4.w;
    }
  }
  float4 wva = w24[s * 2], wvb = w24[s * 2 + 1];
  float tq[8];
#pragma unroll
  for (int q = 0; q < 8; q++) {
    tq[q] = fast_tanh(acc[q][0]) * wva.x + fast_tanh(acc[q][1]) * wva.y +
            fast_tanh(acc[q][2]) * wva.z + fast_tanh(acc[q][3]) * wva.w +
            fast_tanh(acc[q][4]) * wvb.x + fast_tanh(acc[q][5]) * wvb.y +
            fast_tanh(acc[q][6]) * wvb.z + fast_tanh(acc[q][7]) * wvb.w;
  }
#pragma unroll
  for (int q = 0; q < 8; q++) {
    tq[q] += __shfl_xor(tq[q], 1);
    tq[q] += __shfl_xor(tq[q], 2);
    tq[q] += __shfl_xor(tq[q], 4);
  }
  float mine = tq[0];
  mine = (s == 1) ? tq[1] : mine;
  mine = (s == 2) ? tq[2] : mine;
  mine = (s == 3) ? tq[3] : mine;
  mine = (s == 4) ? tq[4] : mine;
  mine = (s == 5) ? tq[5] : mine;
  mine = (s == 6) ? tq[6] : mine;
  mine = (s == 7) ? tq[7] : mine;
  rws[p] = fast_sigmoid(mine + b2_[0]);
}

// ---------------------------------------------------------------------------
// Standalone xproj (layer 0): xproj = xh @ wl -> [N,256], fused di/dj.
__global__ __launch_bounds__(256) void k_xproj(
    const float* __restrict__ xh, const float* __restrict__ wl, const float* __restrict__ wa,
    float* __restrict__ xproj, float* __restrict__ di, float* __restrict__ dj) {
  __shared__ float xsT[64][20];
  int t = threadIdx.x, lane = t & 63, w = t >> 6;
  int n0 = blockIdx.x * 16;
  const float4* xh4 = (const float4*)xh;
  {
    int m = t & 15, k4 = t >> 4;
    float4 xv = xh4[(n0 + m) * 16 + k4];
    xsT[k4 * 4 + 0][m] = xv.x;
    xsT[k4 * 4 + 1][m] = xv.y;
    xsT[k4 * 4 + 2][m] = xv.z;
    xsT[k4 * 4 + 3][m] = xv.w;
  }
  __syncthreads();
  float acc[16];
#pragma unroll
  for (int m = 0; m < 16; m++) acc[m] = 0.f;
  for (int k = 0; k < 64; k++) {
    float wv = wl[k * 256 + t];
    float4 xa = *(const float4*)&xsT[k][0];
    float4 xb = *(const float4*)&xsT[k][4];
    float4 xc = *(const float4*)&xsT[k][8];
    float4 xd = *(const float4*)&xsT[k][12];
    acc[0] += xa.x * wv; acc[1] += xa.y * wv; acc[2] += xa.z * wv; acc[3] += xa.w * wv;
    acc[4] += xb.x * wv; acc[5] += xb.y * wv; acc[6] += xb.z * wv; acc[7] += xb.w * wv;
    acc[8] += xc.x * wv; acc[9] += xc.y * wv; acc[10] += xc.z * wv; acc[11] += xc.w * wv;
    acc[12] += xd.x * wv; acc[13] += xd.y * wv; acc[14] += xd.z * wv; acc[15] += xd.w * wv;
  }
  float wai = wa[lane], waj = wa[64 + lane];
#pragma unroll
  for (int m = 0; m < 16; m++) {
    xproj[(n0 + m) * 256 + t] = acc[m];
    float vi = acc[m] * wai;
    float vj = acc[m] * waj;
#pragma unroll
    for (int off = 32; off; off >>= 1) { vi += __shfl_xor(vi, off); vj += __shfl_xor(vj, off); }
    if (lane == 0) { di[(n0 + m) * 4 + w] = vi; dj[(n0 + m) * 4 + w] = vj; }
  }
}

// ---------------------------------------------------------------------------
// Edge-parallel p computation: ps[i] = exp(leaky(di[r]+dj[c]+dev)*rw), once per
// edge; accumulates global softmax denominator via block-reduced atomics.
__global__ __launch_bounds__(256) void k_pexp(
    const int2* __restrict__ rcs, const float4* __restrict__ devs4,
    const float* __restrict__ rws, const float* __restrict__ di,
    const float* __restrict__ dj, int layer,
    float4* __restrict__ ps4, float* __restrict__ gsum_l) {
  __shared__ float wred[4][4];
  int t = threadIdx.x, lane = t & 63, w = t >> 6;
  int i = blockIdx.x * 256 + t;  // EE % 256 == 0
  int2 rc = rcs[i];
  float4 dv = devs4[i];
  float dev = (layer == 0) ? dv.x : ((layer == 1) ? dv.y : dv.z);
  float rv = rws[i];
  float4 dr = ((const float4*)di)[rc.x];
  float4 djc = ((const float4*)dj)[rc.y];
  float z0 = dr.x + djc.x + dev, z1 = dr.y + djc.y + dev;
  float z2 = dr.z + djc.z + dev, z3 = dr.w + djc.w + dev;
  z0 = ((z0 >= 0.f) ? z0 : 0.2f * z0) * rv;
  z1 = ((z1 >= 0.f) ? z1 : 0.2f * z1) * rv;
  z2 = ((z2 >= 0.f) ? z2 : 0.2f * z2) * rv;
  z3 = ((z3 >= 0.f) ? z3 : 0.2f * z3) * rv;
  float4 pv;
  pv.x = __expf(z0); pv.y = __expf(z1); pv.z = __expf(z2); pv.w = __expf(z3);
  ps4[i] = pv;
  float sh[4] = {pv.x, pv.y, pv.z, pv.w};
#pragma unroll
  for (int h = 0; h < 4; h++) {
    float v = sh[h];
#pragma unroll
    for (int off = 32; off; off >>= 1) v += __shfl_xor(v, off);
    if (lane == 0) wred[w][h] = v;
  }
  __syncthreads();
  if (t < 4) atomicAdd(&gsum_l[t], wred[0][t] + wred[1][t] + wred[2][t] + wred[3][t]);
}

// ---------------------------------------------------------------------------
// Streaming aggregation: wave per node, 2 slots x 2-deep unroll. No gathers:
// ps4 and efs are both indexed by the monotonically increasing sorted index.
__global__ __launch_bounds__(256) void k_agg(
    const int* __restrict__ rowptr, const float4* __restrict__ ps4,
    const float* __restrict__ efs,
    float* __restrict__ sagg, float* __restrict__ tagg) {
  int t = threadIdx.x, lane = t & 63, wv = t >> 6;
  int n = blockIdx.x * 4 + wv;
  int c = lane & 31, slot = lane >> 5;
  float a0 = 0.f, a1 = 0.f, a2 = 0.f, a3 = 0.f;
  float s0 = 0.f, s1 = 0.f, s2 = 0.f, s3 = 0.f;
  int beg = rowptr[n], end = rowptr[n + 1];
  int i = beg + slot;
  for (; i + 2 < end; i += 4) {
    float4 pa = ps4[i];
    float eva = efs[(size_t)i * 32 + c];
    float4 pb = ps4[i + 2];
    float evb = efs[(size_t)(i + 2) * 32 + c];
    a0 += pa.x * eva + pb.x * evb;
    a1 += pa.y * eva + pb.y * evb;
    a2 += pa.z * eva + pb.z * evb;
    a3 += pa.w * eva + pb.w * evb;
    s0 += pa.x + pb.x; s1 += pa.y + pb.y;
    s2 += pa.z + pb.z; s3 += pa.w + pb.w;
  }
  if (i < end) {
    float4 pa = ps4[i];
    float eva = efs[(size_t)i * 32 + c];
    a0 += pa.x * eva; a1 += pa.y * eva; a2 += pa.z * eva; a3 += pa.w * eva;
    s0 += pa.x; s1 += pa.y; s2 += pa.z; s3 += pa.w;
  }
  a0 += __shfl_xor(a0, 32); a1 += __shfl_xor(a1, 32);
  a2 += __shfl_xor(a2, 32); a3 += __shfl_xor(a3, 32);
  s0 += __shfl_xor(s0, 32); s1 += __shfl_xor(s1, 32);
  s2 += __shfl_xor(s2, 32); s3 += __shfl_xor(s3, 32);
  if (slot == 0) {
    tagg[n * 128 + 0 * 32 + c] = a0;
    tagg[n * 128 + 1 * 32 + c] = a1;
    tagg[n * 128 + 2 * 32 + c] = a2;
    tagg[n * 128 + 3 * 32 + c] = a3;
    if (c < 4) {
      float sv = (c == 0) ? s0 : (c == 1) ? s1 : (c == 2) ? s2 : s3;
      sagg[n * 4 + c] = sv;
    }
  }
}

// ---------------------------------------------------------------------------
// Fused node update + next-layer xproj (+di/dj); applies 1/gsum normalization.
template <bool DO_XPROJ>
__global__ __launch_bounds__(256) void k_update_fused(
    const float* __restrict__ xproj, const float* __restrict__ sagg,
    const float* __restrict__ tagg, const float* __restrict__ gsum_l,
    const float* __restrict__ we, const float* __restrict__ wo, const float* __restrict__ wob,
    const float* __restrict__ wl_next, const float* __restrict__ wa_next,
    float* __restrict__ xh_out, float* __restrict__ xproj_out,
    float* __restrict__ di, float* __restrict__ dj) {
  __shared__ float tsT[128][20];
  __shared__ float usT[64][20];
  __shared__ float xhT[64][20];
  __shared__ float ss[16][4];
  int t = threadIdx.x, lane = t & 63, w = t >> 6;
  int n0 = blockIdx.x * 16;
  float4 gs = *((const float4*)gsum_l);
  float inv0 = 1.0f / gs.x, inv1 = 1.0f / gs.y, inv2 = 1.0f / gs.z, inv3 = 1.0f / gs.w;
  const float4* tagg4 = (const float4*)tagg;
  for (int i = t; i < 16 * 32; i += 256) {
    int m = i & 15, k4 = i >> 4;
    float invh = (k4 < 8) ? inv0 : (k4 < 16) ? inv1 : (k4 < 24) ? inv2 : inv3;
    float4 tv = tagg4[(n0 + m) * 32 + k4];
    tsT[k4 * 4 + 0][m] = tv.x * invh;
    tsT[k4 * 4 + 1][m] = tv.y * invh;
    tsT[k4 * 4 + 2][m] = tv.z * invh;
    tsT[k4 * 4 + 3][m] = tv.w * invh;
  }
  if (t < 64) {
    int hh = t & 3;
    float invh = (hh == 0) ? inv0 : (hh == 1) ? inv1 : (hh == 2) ? inv2 : inv3;
    ss[t >> 2][hh] = sagg[n0 * 4 + t] * invh;
  }
  __syncthreads();
  int j = lane, grp = w;
  float u0 = 0.f, u1 = 0.f, u2 = 0.f, u3 = 0.f;
#pragma unroll
  for (int h = 0; h < 4; h++) {
    u0 += xproj[(n0 + grp * 4 + 0) * 256 + h * 64 + j] * ss[grp * 4 + 0][h];
    u1 += xproj[(n0 + grp * 4 + 1) * 256 + h * 64 + j] * ss[grp * 4 + 1][h];
    u2 += xproj[(n0 + grp * 4 + 2) * 256 + h * 64 + j] * ss[grp * 4 + 2][h];
    u3 += xproj[(n0 + grp * 4 + 3) * 256 + h * 64 + j] * ss[grp * 4 + 3][h];
  }
  for (int hc = 0; hc < 128; hc++) {
    float wv = we[(hc & 31) * 256 + (hc >> 5) * 64 + j];
    float4 tv = *(const float4*)&tsT[hc][grp * 4];
    u0 += tv.x * wv; u1 += tv.y * wv; u2 += tv.z * wv; u3 += tv.w * wv;
  }
  *(float4*)&usT[j][grp * 4] = make_float4(u0 * 0.25f, u1 * 0.25f, u2 * 0.25f, u3 * 0.25f);
  __syncthreads();
  float ob = wob[j];
  float o0 = ob, o1 = ob, o2 = ob, o3 = ob;
  for (int k = 0; k < 64; k++) {
    float wv = wo[k * 64 + j];
    float4 uv = *(const float4*)&usT[k][grp * 4];
    o0 += uv.x * wv; o1 += uv.y * wv; o2 += uv.z * wv; o3 += uv.w * wv;
  }
  o0 = fmaxf(o0, 0.f); o1 = fmaxf(o1, 0.f); o2 = fmaxf(o2, 0.f); o3 = fmaxf(o3, 0.f);
  if (!DO_XPROJ) {
    xh_out[(n0 + grp * 4 + 0) * 64 + j] = o0;
    xh_out[(n0 + grp * 4 + 1) * 64 + j] = o1;
    xh_out[(n0 + grp * 4 + 2) * 64 + j] = o2;
    xh_out[(n0 + grp * 4 + 3) * 64 + j] = o3;
    return;
  }
  xhT[j][grp * 4 + 0] = o0;
  xhT[j][grp * 4 + 1] = o1;
  xhT[j][grp * 4 + 2] = o2;
  xhT[j][grp * 4 + 3] = o3;
  __syncthreads();
  float acc[16];
#pragma unroll
  for (int m = 0; m < 16; m++) acc[m] = 0.f;
  for (int k = 0; k < 64; k++) {
    float wv = wl_next[k * 256 + t];
    float4 xa = *(const float4*)&xhT[k][0];
    float4 xb = *(const float4*)&xhT[k][4];
    float4 xc = *(const float4*)&xhT[k][8];
    float4 xd = *(const float4*)&xhT[k][12];
    acc[0] += xa.x * wv; acc[1] += xa.y * wv; acc[2] += xa.z * wv; acc[3] += xa.w * wv;
    acc[4] += xb.x * wv; acc[5] += xb.y * wv; acc[6] += xb.z * wv; acc[7] += xb.w * wv;
    acc[8] += xc.x * wv; acc[9] += xc.y * wv; acc[10] += xc.z * wv; acc[11] += xc.w * wv;
    acc[12] += xd.x * wv; acc[13] += xd.y * wv; acc[14] += xd.z * wv; acc[15] += xd.w * wv;
  }
  float wai = wa_next[lane], waj = wa_next[64 + lane];
#pragma unroll
  for (int m = 0; m < 16; m++) {
    xproj_out[(n0 + m) * 256 + t] = acc[m];
    float vi = acc[m] * wai;
    float vj = acc[m] * waj;
#pragma unroll
    for (int off = 32; off; off >>= 1) { vi += __shfl_xor(vi, off); vj += __shfl_xor(vj, off); }
    if (lane == 0) { di[(n0 + m) * 4 + w] = vi; dj[(n0 + m) * 4 + w] = vj; }
  }
}

// ---------------------------------------------------------------------------
// Output layer: Linear(64,128)+ReLU+Linear(128,256)+LayerNorm(256). 8 nodes/block.
#define OPN 8
__global__ __launch_bounds__(256) void k_out(
    const float* __restrict__ xh, const float* __restrict__ w1, const float* __restrict__ b1,
    const float* __restrict__ w2, const float* __restrict__ b2,
    const float* __restrict__ g, const float* __restrict__ beta,
    float* __restrict__ out) {
  __shared__ float xsT[64][12];
  __shared__ float hsT[128][12];
  __shared__ float wp[4], wq[4];
  int t = threadIdx.x, lane = t & 63, w = t >> 6;
  int n0 = blockIdx.x * OPN;
  const float4* xh4 = (const float4*)xh;
  if (t < 128) {
    int m = t >> 4, k4 = t & 15;
    float4 xv = xh4[(n0 + m) * 16 + k4];
    xsT[k4 * 4 + 0][m] = xv.x;
    xsT[k4 * 4 + 1][m] = xv.y;
    xsT[k4 * 4 + 2][m] = xv.z;
    xsT[k4 * 4 + 3][m] = xv.w;
  }
  __syncthreads();
  for (int i = t; i < OPN * 128; i += 256) {
    int m = i >> 7, jj = i & 127;
    float a = b1[jj];
#pragma unroll
    for (int k = 0; k < 64; k++) a += xsT[k][m] * w1[k * 128 + jj];
    hsT[jj][m] = fmaxf(a, 0.f);
  }
  __syncthreads();
  float o[OPN];
  float bb = b2[t];
#pragma unroll
  for (int m = 0; m < OPN; m++) o[m] = bb;
  for (int k = 0; k < 128; k++) {
    float wv = w2[k * 256 + t];
    float4 ha = *(const float4*)&hsT[k][0];
    float4 hb = *(const float4*)&hsT[k][4];
    o[0] += ha.x * wv; o[1] += ha.y * wv; o[2] += ha.z * wv; o[3] += ha.w * wv;
    o[4] += hb.x * wv; o[5] += hb.y * wv; o[6] += hb.z * wv; o[7] += hb.w * wv;
  }
  float gv = g[t], bv = beta[t];
#pragma unroll
  for (int m = 0; m < OPN; m++) {
    float v = o[m], vv = o[m] * o[m];
#pragma unroll
    for (int off = 32; off; off >>= 1) { v += __shfl_xor(v, off); vv += __shfl_xor(vv, off); }
    if (lane == 0) { wp[w] = v; wq[w] = vv; }
    __syncthreads();
    float mean = (wp[0] + wp[1] + wp[2] + wp[3]) * (1.f / 256.f);
    float ex2 = (wq[0] + wq[1] + wq[2] + wq[3]) * (1.f / 256.f);
    float var = ex2 - mean * mean;
    __syncthreads();
    out[(n0 + m) * 256 + t] = (o[m] - mean) * rsqrtf(var + 1e-5f) * gv + bv;
  }
}

// ---------------------------------------------------------------------------
extern "C" void kernel_launch(void* const* d_in, const int* in_sizes, int n_in,
                              void* d_out, int out_size, void* d_ws, size_t ws_size,
                              hipStream_t stream) {
  const float* x         = (const float*)d_in[0];
  const float* edge_attr = (const float*)d_in[1];
  const int*   ei        = (const int*)d_in[2];
  const float* ne_w1 = (const float*)d_in[3];
  const float* ne_b1 = (const float*)d_in[4];
  const float* ne_w2 = (const float*)d_in[5];
  const float* ne_b2 = (const float*)d_in[6];
  const float* ne_g  = (const float*)d_in[7];
  const float* ne_be = (const float*)d_in[8];
  const float* ee_w1 = (const float*)d_in[9];
  const float* ee_b1 = (const float*)d_in[10];
  const float* ee_w2 = (const float*)d_in[11];
  const float* ee_b2 = (const float*)d_in[12];
  const float* ee_g  = (const float*)d_in[13];
  const float* ee_be = (const float*)d_in[14];
  const float* ra_w1 = (const float*)d_in[15];
  const float* ra_b1 = (const float*)d_in[16];
  const float* ra_w2 = (const float*)d_in[17];
  const float* ra_b2 = (const float*)d_in[18];
  const float* gat_wl  = (const float*)d_in[19];
  const float* gat_wa  = (const float*)d_in[20];
  const float* gat_we  = (const float*)d_in[21];
  const float* gat_wo  = (const float*)d_in[22];
  const float* gat_wob = (const float*)d_in[23];
  const float* ow_1 = (const float*)d_in[24];
  const float* ob_1 = (const float*)d_in[25];
  const float* ow_2 = (const float*)d_in[26];
  const float* ob_2 = (const float*)d_in[27];
  const float* o_g  = (const float*)d_in[28];
  const float* o_be = (const float*)d_in[29];
  float* out = (float*)d_out;

  char* wsb = (char*)d_ws;
  size_t off = 0;
  auto af = [&](size_t elems) -> float* { float* p = (float*)(wsb + off); off += elems * sizeof(float); return p; };
  auto ai = [&](size_t elems) -> int*   { int*   p = (int*)(wsb + off);   off += elems * sizeof(int);   return p; };

  float* h      = af((size_t)NN * 64);
  float* xh2    = af((size_t)NN * 64);
  float* efs    = af((size_t)EE * 32);   // ef rows, SORTED by destination node
  float* devs   = af((size_t)EE * 4);    // interleaved (d0,d1,d2,_) per sorted edge
  float* rws    = af((size_t)EE);        // risk weights, sorted
  float* ps     = af((size_t)EE * 4);    // per-edge softmax numerators, sorted
  float* xprojA = af((size_t)NN * 256);
  float* xprojB = af((size_t)NN * 256);  // aliased as hnode before layer 1
  float* di     = af((size_t)NN * 4);
  float* dj     = af((size_t)NN * 4);
  float* sagg   = af((size_t)NN * 4);
  float* tagg   = af((size_t)NN * 128);
  float* gsum   = af(12);                // 3 layers x 4 heads softmax denominators
  int* rcs    = ai(2 * (size_t)EE);      // (row, col) per sorted edge
  int* counts = ai(NN);
  int* rowptr = ai(NN + 1);
  int* cursor = ai(NN);
  float* hnode = xprojB;  // consumed by k_risk_edge before xprojB's first write
  (void)ws_size; (void)n_in; (void)in_sizes; (void)out_size;

  hipMemsetAsync(counts, 0, NN * sizeof(int), stream);
  hipMemsetAsync(gsum, 0, 12 * sizeof(float), stream);
  k_hist<<<EE / 256, 256, 0, stream>>>(ei, counts);
  k_node_enc<<<(NN + 255) / 256, 256, 0, stream>>>(x, ne_w1, ne_b1, ne_w2, ne_b2, ne_g, ne_be, h);
  k_scan<<<1, 1024, 0, stream>>>(counts, rowptr, cursor);
  k_edge_enc<<<EE / 256, 256, 0, stream>>>(edge_attr, ee_w1, ee_b1, ee_w2, ee_b2, ee_g, ee_be,
                                           gat_wa, ei, cursor, efs, (float4*)devs, (int2*)rcs);
  k_risk_node<<<NN / 16, 256, 0, stream>>>(h, ra_w1, ra_b1, hnode);
  k_risk_edge<<<EE / 256, 256, 0, stream>>>(hnode, efs, (const int2*)rcs,
                                            ra_w1 + 64 * 64, ra_w2, ra_b2, rws);
  k_xproj<<<NN / 16, 256, 0, stream>>>(h, gat_wl, gat_wa, xprojA, di, dj);

  float* xp_cur = xprojA;
  float* xp_nxt = xprojB;
  for (int l = 0; l < 3; l++) {
    const float* we  = gat_we + (size_t)l * 32 * 256;
    const float* wo  = gat_wo + (size_t)l * 64 * 64;
    const float* wob = gat_wob + (size_t)l * 64;
    float* gsum_l = gsum + l * 4;

    k_pexp<<<EE / 256, 256, 0, stream>>>((const int2*)rcs, (const float4*)devs, rws,
                                         di, dj, l, (float4*)ps, gsum_l);
    k_agg<<<NN / 4, 256, 0, stream>>>(rowptr, (const float4*)ps, efs, sagg, tagg);
    if (l < 2) {
      const float* wl_n = gat_wl + (size_t)(l + 1) * 64 * 256;
      const float* wa_n = gat_wa + (size_t)(l + 1) * 160;
      k_update_fused<true><<<NN / 16, 256, 0, stream>>>(
          xp_cur, sagg, tagg, gsum_l, we, wo, wob, wl_n, wa_n, nullptr, xp_nxt, di, dj);
      float* tmp = xp_cur; xp_cur = xp_nxt; xp_nxt = tmp;
    } else {
      k_update_fused<false><<<NN / 16, 256, 0, stream>>>(
          xp_cur, sagg, tagg, gsum_l, we, wo, wob, nullptr, nullptr, xh2, nullptr, nullptr, nullptr);
    }
  }

  k_out<<<NN / OPN, 256, 0, stream>>>(xh2, ow_1, ob_1, ow_2, ob_2, o_g, o_be, out);
}

// Round 8
// 531.054 us; speedup vs baseline: 1.2492x; 1.0294x over previous
//
#include <hip/hip_runtime.h>
#include <math.h>

#define NN 20000
#define EE 320000
#define HID 64
#define EHID 32
#define HEADS 4

__device__ __forceinline__ float fast_tanh(float x) {
  float e = __expf(2.f * x);
  return 1.f - 2.f * __builtin_amdgcn_rcpf(e + 1.f);
}
__device__ __forceinline__ float fast_sigmoid(float x) {
  return __builtin_amdgcn_rcpf(1.f + __expf(-x));
}
__device__ __forceinline__ float bcast8(float v, int q) {
  // broadcast within 8-lane group: src lane = (lane & 0b11000) | q (BitMode swizzle)
  switch (q) {
    case 0: return __int_as_float(__builtin_amdgcn_ds_swizzle(__float_as_int(v), (0 << 5) | 0x18));
    case 1: return __int_as_float(__builtin_amdgcn_ds_swizzle(__float_as_int(v), (1 << 5) | 0x18));
    case 2: return __int_as_float(__builtin_amdgcn_ds_swizzle(__float_as_int(v), (2 << 5) | 0x18));
    case 3: return __int_as_float(__builtin_amdgcn_ds_swizzle(__float_as_int(v), (3 << 5) | 0x18));
    case 4: return __int_as_float(__builtin_amdgcn_ds_swizzle(__float_as_int(v), (4 << 5) | 0x18));
    case 5: return __int_as_float(__builtin_amdgcn_ds_swizzle(__float_as_int(v), (5 << 5) | 0x18));
    case 6: return __int_as_float(__builtin_amdgcn_ds_swizzle(__float_as_int(v), (6 << 5) | 0x18));
    default: return __int_as_float(__builtin_amdgcn_ds_swizzle(__float_as_int(v), (7 << 5) | 0x18));
  }
}

// ---------------------------------------------------------------------------
// Node encoder: Linear(9,32)+ReLU+Linear(32,64)+LayerNorm(64). Thread per node.
__global__ __launch_bounds__(256) void k_node_enc(
    const float* __restrict__ x, const float* __restrict__ w1, const float* __restrict__ b1,
    const float* __restrict__ w2, const float* __restrict__ b2,
    const float* __restrict__ g, const float* __restrict__ beta,
    float* __restrict__ h) {
  int n = blockIdx.x * blockDim.x + threadIdx.x;
  if (n >= NN) return;
  float xin[9];
#pragma unroll
  for (int k = 0; k < 9; k++) xin[k] = x[n * 9 + k];
  float hid[32];
#pragma unroll
  for (int j = 0; j < 32; j++) {
    float a = b1[j];
#pragma unroll
    for (int k = 0; k < 9; k++) a += xin[k] * w1[k * 32 + j];
    hid[j] = fmaxf(a, 0.f);
  }
  float o[64];
  float s = 0.f;
  for (int j = 0; j < 64; j++) {
    float a = b2[j];
#pragma unroll
    for (int k = 0; k < 32; k++) a += hid[k] * w2[k * 64 + j];
    o[j] = a;
    s += a;
  }
  float m = s * (1.f / 64.f);
  float v = 0.f;
  for (int j = 0; j < 64; j++) { float d = o[j] - m; v += d * d; }
  v *= (1.f / 64.f);
  float inv = rsqrtf(v + 1e-5f);
#pragma unroll
  for (int j4 = 0; j4 < 16; j4++) {
    float4 r;
    r.x = (o[j4 * 4 + 0] - m) * inv * g[j4 * 4 + 0] + beta[j4 * 4 + 0];
    r.y = (o[j4 * 4 + 1] - m) * inv * g[j4 * 4 + 1] + beta[j4 * 4 + 1];
    r.z = (o[j4 * 4 + 2] - m) * inv * g[j4 * 4 + 2] + beta[j4 * 4 + 2];
    r.w = (o[j4 * 4 + 3] - m) * inv * g[j4 * 4 + 3] + beta[j4 * 4 + 3];
    ((float4*)&h[n * 64])[j4] = r;
  }
}

// ---------------------------------------------------------------------------
// CSR histogram over col
__global__ __launch_bounds__(256) void k_hist(const int* __restrict__ ei, int* __restrict__ counts) {
  int e = blockIdx.x * 256 + threadIdx.x;
  if (e < EE) atomicAdd(&counts[ei[EE + e]], 1);
}
// shfl-based single-block scan: 1024 threads x 20 elements each.
__global__ __launch_bounds__(1024) void k_scan(
    const int* __restrict__ counts, int* __restrict__ rowptr, int* __restrict__ cursor) {
  __shared__ int wsum[16];
  int t = threadIdx.x, lane = t & 63, w = t >> 6;
  const int CH = 20;  // 1024*20 >= NN
  int base_i = t * CH;
  int local = 0;
  for (int i = 0; i < CH; i++) {
    int idx = base_i + i;
    if (idx < NN) local += counts[idx];
  }
  int v = local;
#pragma unroll
  for (int off = 1; off < 64; off <<= 1) {
    int u = __shfl_up(v, off);
    if (lane >= off) v += u;
  }
  if (lane == 63) wsum[w] = v;
  __syncthreads();
  int wbase = 0;
  for (int i = 0; i < w; i++) wbase += wsum[i];
  int run = wbase + v - local;  // exclusive prefix
  for (int i = 0; i < CH; i++) {
    int idx = base_i + i;
    if (idx < NN) {
      rowptr[idx] = run;
      cursor[idx] = run;
      run += counts[idx];
    }
  }
  if (t == 1023) rowptr[NN] = EE;
}

// ---------------------------------------------------------------------------
// Edge encoder, SORTED-output: computes ef/dev, grabs CSR slot via cursor, and
// writes efs/devs4/rcs in destination-node order. Thread per edge.
__global__ __launch_bounds__(256) void k_edge_enc(
    const float* __restrict__ ea, const float* __restrict__ w1, const float* __restrict__ b1,
    const float* __restrict__ w2, const float* __restrict__ b2,
    const float* __restrict__ g, const float* __restrict__ beta,
    const float* __restrict__ gat_wa, const int* __restrict__ ei,
    int* __restrict__ cursor,
    float* __restrict__ efs, float4* __restrict__ devs4, int2* __restrict__ rcs) {
  int e = blockIdx.x * blockDim.x + threadIdx.x;
  if (e >= EE) return;
  int row = ei[e], col = ei[EE + e];
  int pos = atomicAdd(&cursor[col], 1);
  float4 xin = ((const float4*)ea)[e];
  float hid[16];
#pragma unroll
  for (int j = 0; j < 16; j++) {
    float a = b1[j];
    a += xin.x * w1[0 * 16 + j];
    a += xin.y * w1[1 * 16 + j];
    a += xin.z * w1[2 * 16 + j];
    a += xin.w * w1[3 * 16 + j];
    hid[j] = fmaxf(a, 0.f);
  }
  float o[32];
  float s = 0.f;
#pragma unroll
  for (int j = 0; j < 32; j++) {
    float a = b2[j];
#pragma unroll
    for (int k = 0; k < 16; k++) a += hid[k] * w2[k * 32 + j];
    o[j] = a;
    s += a;
  }
  float m = s * (1.f / 32.f);
  float v = 0.f;
#pragma unroll
  for (int j = 0; j < 32; j++) { float d = o[j] - m; v += d * d; }
  v *= (1.f / 32.f);
  float inv = rsqrtf(v + 1e-5f);
  float d0 = 0.f, d1 = 0.f, d2 = 0.f;
  float vn[32];
#pragma unroll
  for (int j = 0; j < 32; j++) {
    vn[j] = (o[j] - m) * inv * g[j] + beta[j];
    d0 += vn[j] * gat_wa[0 * 160 + 128 + j];
    d1 += vn[j] * gat_wa[1 * 160 + 128 + j];
    d2 += vn[j] * gat_wa[2 * 160 + 128 + j];
  }
#pragma unroll
  for (int j4 = 0; j4 < 8; j4++) {
    float4 r;
    r.x = vn[j4 * 4 + 0]; r.y = vn[j4 * 4 + 1]; r.z = vn[j4 * 4 + 2]; r.w = vn[j4 * 4 + 3];
    ((float4*)&efs[(size_t)pos * 32])[j4] = r;
  }
  devs4[pos] = make_float4(d0, d1, d2, 0.f);
  rcs[pos] = make_int2(row, col);
}

// ---------------------------------------------------------------------------
// Risk MLP part 1: hnode = h @ ra_w1[0:64,:] + b1. 16 nodes/block, transposed LDS.
__global__ __launch_bounds__(256) void k_risk_node(
    const float* __restrict__ h, const float* __restrict__ w1, const float* __restrict__ b1,
    float* __restrict__ hnode) {
  __shared__ float xsT[64][20];
  int t = threadIdx.x;
  int n0 = blockIdx.x * 16;
  const float4* h4 = (const float4*)h;
  {
    int m = t & 15, k4 = t >> 4;
    float4 xv = h4[(n0 + m) * 16 + k4];
    xsT[k4 * 4 + 0][m] = xv.x;
    xsT[k4 * 4 + 1][m] = xv.y;
    xsT[k4 * 4 + 2][m] = xv.z;
    xsT[k4 * 4 + 3][m] = xv.w;
  }
  __syncthreads();
  int j = t & 63, grp = t >> 6;
  float bv = b1[j];
  float a0 = bv, a1 = bv, a2 = bv, a3 = bv;
  for (int k = 0; k < 64; k++) {
    float wv = w1[k * 64 + j];
    float4 xv = *(const float4*)&xsT[k][grp * 4];
    a0 += xv.x * wv; a1 += xv.y * wv; a2 += xv.z * wv; a3 += xv.w * wv;
  }
  hnode[(n0 + grp * 4 + 0) * 64 + j] = a0;
  hnode[(n0 + grp * 4 + 1) * 64 + j] = a1;
  hnode[(n0 + grp * 4 + 2) * 64 + j] = a2;
  hnode[(n0 + grp * 4 + 3) * 64 + j] = a3;
}

// ---------------------------------------------------------------------------
// Risk MLP part 2, register-tiled (sorted domain): 8-lane group = 8 edges.
__global__ __launch_bounds__(256) void k_risk_edge(
    const float* __restrict__ hnode, const float* __restrict__ efs, const int2* __restrict__ rcs,
    const float* __restrict__ w1e, const float* __restrict__ w2, const float* __restrict__ b2_,
    float* __restrict__ rws) {
  int t = threadIdx.x, lane = t & 63;
  int s = lane & 7;
  int p = blockIdx.x * 256 + t;  // own sorted edge
  int myrow = rcs[p].x;
  const float4* hnode4 = (const float4*)hnode;
  const float4* efs4 = (const float4*)efs;
  const float4* w1e4 = (const float4*)w1e;
  const float4* w24 = (const float4*)w2;
  float ev[32];
#pragma unroll
  for (int i = 0; i < 8; i++) {
    float4 tmp = efs4[(size_t)p * 8 + i];
    ev[i * 4 + 0] = tmp.x; ev[i * 4 + 1] = tmp.y; ev[i * 4 + 2] = tmp.z; ev[i * 4 + 3] = tmp.w;
  }
  int rowq[8];
#pragma unroll
  for (int q = 0; q < 8; q++)
    rowq[q] = __float_as_int(bcast8(__int_as_float(myrow), q));
  float acc[8][8];
#pragma unroll
  for (int q = 0; q < 8; q++) {
    float4 ha = hnode4[(size_t)rowq[q] * 16 + s * 2];
    float4 hb = hnode4[(size_t)rowq[q] * 16 + s * 2 + 1];
    acc[q][0] = ha.x; acc[q][1] = ha.y; acc[q][2] = ha.z; acc[q][3] = ha.w;
    acc[q][4] = hb.x; acc[q][5] = hb.y; acc[q][6] = hb.z; acc[q][7] = hb.w;
  }
#pragma unroll
  for (int k = 0; k < 32; k++) {
    float4 wa4 = w1e4[k * 16 + s * 2];
    float4 wb4 = w1e4[k * 16 + s * 2 + 1];
#pragma unroll
    for (int q = 0; q < 8; q++) {
      float ekq = bcast8(ev[k], q);
      acc[q][0] += ekq * wa4.x; acc[q][1] += ekq * wa4.y;
      acc[q][2] += ekq * wa4.z; acc[q][3] += ekq * wa4.w;
      acc[q][4] += ekq * wb4.x; acc[q][5] += ekq * wb4.y;
      acc[q][6] += ekq * wb4.z; acc[q][7] += ekq * wb4.w;
    }
  }
  float4 wva = w24[s * 2], wvb = w24[s * 2 + 1];
  float tq[8];
#pragma unroll
  for (int q = 0; q < 8; q++) {
    tq[q] = fast_tanh(acc[q][0]) * wva.x + fast_tanh(acc[q][1]) * wva.y +
            fast_tanh(acc[q][2]) * wva.z + fast_tanh(acc[q][3]) * wva.w +
            fast_tanh(acc[q][4]) * wvb.x + fast_tanh(acc[q][5]) * wvb.y +
            fast_tanh(acc[q][6]) * wvb.z + fast_tanh(acc[q][7]) * wvb.w;
  }
#pragma unroll
  for (int q = 0; q < 8; q++) {
    tq[q] += __shfl_xor(tq[q], 1);
    tq[q] += __shfl_xor(tq[q], 2);
    tq[q] += __shfl_xor(tq[q], 4);
  }
  float mine = tq[0];
  mine = (s == 1) ? tq[1] : mine;
  mine = (s == 2) ? tq[2] : mine;
  mine = (s == 3) ? tq[3] : mine;
  mine = (s == 4) ? tq[4] : mine;
  mine = (s == 5) ? tq[5] : mine;
  mine = (s == 6) ? tq[6] : mine;
  mine = (s == 7) ? tq[7] : mine;
  rws[p] = fast_sigmoid(mine + b2_[0]);
}

// ---------------------------------------------------------------------------
// Standalone xproj (layer 0): xproj = xh @ wl -> [N,256], fused di/dj.
__global__ __launch_bounds__(256) void k_xproj(
    const float* __restrict__ xh, const float* __restrict__ wl, const float* __restrict__ wa,
    float* __restrict__ xproj, float* __restrict__ di, float* __restrict__ dj) {
  __shared__ float xsT[64][20];
  int t = threadIdx.x, lane = t & 63, w = t >> 6;
  int n0 = blockIdx.x * 16;
  const float4* xh4 = (const float4*)xh;
  {
    int m = t & 15, k4 = t >> 4;
    float4 xv = xh4[(n0 + m) * 16 + k4];
    xsT[k4 * 4 + 0][m] = xv.x;
    xsT[k4 * 4 + 1][m] = xv.y;
    xsT[k4 * 4 + 2][m] = xv.z;
    xsT[k4 * 4 + 3][m] = xv.w;
  }
  __syncthreads();
  float acc[16];
#pragma unroll
  for (int m = 0; m < 16; m++) acc[m] = 0.f;
  for (int k = 0; k < 64; k++) {
    float wv = wl[k * 256 + t];
    float4 xa = *(const float4*)&xsT[k][0];
    float4 xb = *(const float4*)&xsT[k][4];
    float4 xc = *(const float4*)&xsT[k][8];
    float4 xd = *(const float4*)&xsT[k][12];
    acc[0] += xa.x * wv; acc[1] += xa.y * wv; acc[2] += xa.z * wv; acc[3] += xa.w * wv;
    acc[4] += xb.x * wv; acc[5] += xb.y * wv; acc[6] += xb.z * wv; acc[7] += xb.w * wv;
    acc[8] += xc.x * wv; acc[9] += xc.y * wv; acc[10] += xc.z * wv; acc[11] += xc.w * wv;
    acc[12] += xd.x * wv; acc[13] += xd.y * wv; acc[14] += xd.z * wv; acc[15] += xd.w * wv;
  }
  float wai = wa[lane], waj = wa[64 + lane];
#pragma unroll
  for (int m = 0; m < 16; m++) {
    xproj[(n0 + m) * 256 + t] = acc[m];
    float vi = acc[m] * wai;
    float vj = acc[m] * waj;
#pragma unroll
    for (int off = 32; off; off >>= 1) { vi += __shfl_xor(vi, off); vj += __shfl_xor(vj, off); }
    if (lane == 0) { di[(n0 + m) * 4 + w] = vi; dj[(n0 + m) * 4 + w] = vj; }
  }
}

// ---------------------------------------------------------------------------
// Edge-parallel p computation: ps[i] = exp(leaky(di[r]+dj[c]+dev)*rw), once per
// edge; accumulates global softmax denominator via block-reduced atomics.
__global__ __launch_bounds__(256) void k_pexp(
    const int2* __restrict__ rcs, const float4* __restrict__ devs4,
    const float* __restrict__ rws, const float* __restrict__ di,
    const float* __restrict__ dj, int layer,
    float4* __restrict__ ps4, float* __restrict__ gsum_l) {
  __shared__ float wred[4][4];
  int t = threadIdx.x, lane = t & 63, w = t >> 6;
  int i = blockIdx.x * 256 + t;  // EE % 256 == 0
  int2 rc = rcs[i];
  float4 dv = devs4[i];
  float dev = (layer == 0) ? dv.x : ((layer == 1) ? dv.y : dv.z);
  float rv = rws[i];
  float4 dr = ((const float4*)di)[rc.x];
  float4 djc = ((const float4*)dj)[rc.y];
  float z0 = dr.x + djc.x + dev, z1 = dr.y + djc.y + dev;
  float z2 = dr.z + djc.z + dev, z3 = dr.w + djc.w + dev;
  z0 = ((z0 >= 0.f) ? z0 : 0.2f * z0) * rv;
  z1 = ((z1 >= 0.f) ? z1 : 0.2f * z1) * rv;
  z2 = ((z2 >= 0.f) ? z2 : 0.2f * z2) * rv;
  z3 = ((z3 >= 0.f) ? z3 : 0.2f * z3) * rv;
  float4 pv;
  pv.x = __expf(z0); pv.y = __expf(z1); pv.z = __expf(z2); pv.w = __expf(z3);
  ps4[i] = pv;
  float sh[4] = {pv.x, pv.y, pv.z, pv.w};
#pragma unroll
  for (int h = 0; h < 4; h++) {
    float v = sh[h];
#pragma unroll
    for (int off = 32; off; off >>= 1) v += __shfl_xor(v, off);
    if (lane == 0) wred[w][h] = v;
  }
  __syncthreads();
  if (t < 4) atomicAdd(&gsum_l[t], wred[0][t] + wred[1][t] + wred[2][t] + wred[3][t]);
}

// ---------------------------------------------------------------------------
// FUSED aggregation + node update (+ next-layer xproj + di/dj).
// Wave wv aggregates nodes n0+wv*4..+3 from the sorted edge stream straight
// into LDS tiles (normalized by 1/gsum), then the block runs the update GEMMs.
template <bool DO_XPROJ>
__global__ __launch_bounds__(256) void k_aggupdate(
    const int* __restrict__ rowptr, const float4* __restrict__ ps4,
    const float* __restrict__ efs, const float* __restrict__ gsum_l,
    const float* __restrict__ xproj,
    const float* __restrict__ we, const float* __restrict__ wo, const float* __restrict__ wob,
    const float* __restrict__ wl_next, const float* __restrict__ wa_next,
    float* __restrict__ xh_out, float* __restrict__ xproj_out,
    float* __restrict__ di, float* __restrict__ dj) {
  __shared__ float tsT[128][20];
  __shared__ float usT[64][20];
  __shared__ float xhT[64][20];
  __shared__ float ss[16][4];
  int t = threadIdx.x, lane = t & 63, wv = t >> 6;
  int n0 = blockIdx.x * 16;
  float4 gs = *((const float4*)gsum_l);
  float inv0 = 1.0f / gs.x, inv1 = 1.0f / gs.y, inv2 = 1.0f / gs.z, inv3 = 1.0f / gs.w;
  int c = lane & 31, slot = lane >> 5;
  // ---- aggregation phase: 4 nodes per wave, streaming sorted edges ----
#pragma unroll
  for (int q = 0; q < 4; q++) {
    int n = n0 + wv * 4 + q;
    int beg = rowptr[n], end = rowptr[n + 1];
    float a0 = 0.f, a1 = 0.f, a2 = 0.f, a3 = 0.f;
    float s0 = 0.f, s1 = 0.f, s2 = 0.f, s3 = 0.f;
    int i = beg + slot;
    for (; i + 2 < end; i += 4) {
      float4 pa = ps4[i];
      float eva = efs[(size_t)i * 32 + c];
      float4 pb = ps4[i + 2];
      float evb = efs[(size_t)(i + 2) * 32 + c];
      a0 += pa.x * eva + pb.x * evb;
      a1 += pa.y * eva + pb.y * evb;
      a2 += pa.z * eva + pb.z * evb;
      a3 += pa.w * eva + pb.w * evb;
      s0 += pa.x + pb.x; s1 += pa.y + pb.y;
      s2 += pa.z + pb.z; s3 += pa.w + pb.w;
    }
    if (i < end) {
      float4 pa = ps4[i];
      float eva = efs[(size_t)i * 32 + c];
      a0 += pa.x * eva; a1 += pa.y * eva; a2 += pa.z * eva; a3 += pa.w * eva;
      s0 += pa.x; s1 += pa.y; s2 += pa.z; s3 += pa.w;
    }
    a0 += __shfl_xor(a0, 32); a1 += __shfl_xor(a1, 32);
    a2 += __shfl_xor(a2, 32); a3 += __shfl_xor(a3, 32);
    s0 += __shfl_xor(s0, 32); s1 += __shfl_xor(s1, 32);
    s2 += __shfl_xor(s2, 32); s3 += __shfl_xor(s3, 32);
    if (slot == 0) {
      int m = wv * 4 + q;
      tsT[0 * 32 + c][m] = a0 * inv0;
      tsT[1 * 32 + c][m] = a1 * inv1;
      tsT[2 * 32 + c][m] = a2 * inv2;
      tsT[3 * 32 + c][m] = a3 * inv3;
      if (c < 4) {
        float sv = (c == 0) ? s0 : (c == 1) ? s1 : (c == 2) ? s2 : s3;
        float iv = (c == 0) ? inv0 : (c == 1) ? inv1 : (c == 2) ? inv2 : inv3;
        ss[m][c] = sv * iv;
      }
    }
  }
  __syncthreads();
  // ---- update phase ----
  int j = lane, grp = wv;
  float u0 = 0.f, u1 = 0.f, u2 = 0.f, u3 = 0.f;
#pragma unroll
  for (int h = 0; h < 4; h++) {
    u0 += xproj[(n0 + grp * 4 + 0) * 256 + h * 64 + j] * ss[grp * 4 + 0][h];
    u1 += xproj[(n0 + grp * 4 + 1) * 256 + h * 64 + j] * ss[grp * 4 + 1][h];
    u2 += xproj[(n0 + grp * 4 + 2) * 256 + h * 64 + j] * ss[grp * 4 + 2][h];
    u3 += xproj[(n0 + grp * 4 + 3) * 256 + h * 64 + j] * ss[grp * 4 + 3][h];
  }
  for (int hc = 0; hc < 128; hc++) {
    float wv2 = we[(hc & 31) * 256 + (hc >> 5) * 64 + j];
    float4 tv = *(const float4*)&tsT[hc][grp * 4];
    u0 += tv.x * wv2; u1 += tv.y * wv2; u2 += tv.z * wv2; u3 += tv.w * wv2;
  }
  *(float4*)&usT[j][grp * 4] = make_float4(u0 * 0.25f, u1 * 0.25f, u2 * 0.25f, u3 * 0.25f);
  __syncthreads();
  float ob = wob[j];
  float o0 = ob, o1 = ob, o2 = ob, o3 = ob;
  for (int k = 0; k < 64; k++) {
    float wv2 = wo[k * 64 + j];
    float4 uv = *(const float4*)&usT[k][grp * 4];
    o0 += uv.x * wv2; o1 += uv.y * wv2; o2 += uv.z * wv2; o3 += uv.w * wv2;
  }
  o0 = fmaxf(o0, 0.f); o1 = fmaxf(o1, 0.f); o2 = fmaxf(o2, 0.f); o3 = fmaxf(o3, 0.f);
  if (!DO_XPROJ) {
    xh_out[(n0 + grp * 4 + 0) * 64 + j] = o0;
    xh_out[(n0 + grp * 4 + 1) * 64 + j] = o1;
    xh_out[(n0 + grp * 4 + 2) * 64 + j] = o2;
    xh_out[(n0 + grp * 4 + 3) * 64 + j] = o3;
    return;
  }
  xhT[j][grp * 4 + 0] = o0;
  xhT[j][grp * 4 + 1] = o1;
  xhT[j][grp * 4 + 2] = o2;
  xhT[j][grp * 4 + 3] = o3;
  __syncthreads();
  float acc[16];
#pragma unroll
  for (int m = 0; m < 16; m++) acc[m] = 0.f;
  for (int k = 0; k < 64; k++) {
    float wv2 = wl_next[k * 256 + t];
    float4 xa = *(const float4*)&xhT[k][0];
    float4 xb = *(const float4*)&xhT[k][4];
    float4 xc = *(const float4*)&xhT[k][8];
    float4 xd = *(const float4*)&xhT[k][12];
    acc[0] += xa.x * wv2; acc[1] += xa.y * wv2; acc[2] += xa.z * wv2; acc[3] += xa.w * wv2;
    acc[4] += xb.x * wv2; acc[5] += xb.y * wv2; acc[6] += xb.z * wv2; acc[7] += xb.w * wv2;
    acc[8] += xc.x * wv2; acc[9] += xc.y * wv2; acc[10] += xc.z * wv2; acc[11] += xc.w * wv2;
    acc[12] += xd.x * wv2; acc[13] += xd.y * wv2; acc[14] += xd.z * wv2; acc[15] += xd.w * wv2;
  }
  float wai = wa_next[lane], waj = wa_next[64 + lane];
#pragma unroll
  for (int m = 0; m < 16; m++) {
    xproj_out[(n0 + m) * 256 + t] = acc[m];
    float vi = acc[m] * wai;
    float vj = acc[m] * waj;
#pragma unroll
    for (int off = 32; off; off >>= 1) { vi += __shfl_xor(vi, off); vj += __shfl_xor(vj, off); }
    if (lane == 0) { di[(n0 + m) * 4 + wv] = vi; dj[(n0 + m) * 4 + wv] = vj; }
  }
}

// ---------------------------------------------------------------------------
// Output layer: Linear(64,128)+ReLU+Linear(128,256)+LayerNorm(256).
// 16 nodes/block for w2 reuse; single-sync LayerNorm.
#define OPN 16
__global__ __launch_bounds__(256) void k_out(
    const float* __restrict__ xh, const float* __restrict__ w1, const float* __restrict__ b1,
    const float* __restrict__ w2, const float* __restrict__ b2,
    const float* __restrict__ g, const float* __restrict__ beta,
    float* __restrict__ out) {
  __shared__ float xsT[64][17];
  __shared__ float hsT[128][20];
  __shared__ float wp[16][4], wq[16][4];
  int t = threadIdx.x, lane = t & 63, w = t >> 6;
  int n0 = blockIdx.x * OPN;
  const float4* xh4 = (const float4*)xh;
  {
    int m = t & 15, k4 = t >> 4;  // 256 threads = 256 float4s
    float4 xv = xh4[(n0 + m) * 16 + k4];
    xsT[k4 * 4 + 0][m] = xv.x;
    xsT[k4 * 4 + 1][m] = xv.y;
    xsT[k4 * 4 + 2][m] = xv.z;
    xsT[k4 * 4 + 3][m] = xv.w;
  }
  __syncthreads();
  for (int i = t; i < OPN * 128; i += 256) {
    int m = i >> 7, jj = i & 127;
    float a = b1[jj];
#pragma unroll
    for (int k = 0; k < 64; k++) a += xsT[k][m] * w1[k * 128 + jj];
    hsT[jj][m] = fmaxf(a, 0.f);
  }
  __syncthreads();
  float o[OPN];
  float bb = b2[t];
#pragma unroll
  for (int m = 0; m < OPN; m++) o[m] = bb;
  for (int k = 0; k < 128; k++) {
    float wv = w2[k * 256 + t];
    float4 h0 = *(const float4*)&hsT[k][0];
    float4 h1 = *(const float4*)&hsT[k][4];
    float4 h2 = *(const float4*)&hsT[k][8];
    float4 h3 = *(const float4*)&hsT[k][12];
    o[0] += h0.x * wv; o[1] += h0.y * wv; o[2] += h0.z * wv; o[3] += h0.w * wv;
    o[4] += h1.x * wv; o[5] += h1.y * wv; o[6] += h1.z * wv; o[7] += h1.w * wv;
    o[8] += h2.x * wv; o[9] += h2.y * wv; o[10] += h2.z * wv; o[11] += h2.w * wv;
    o[12] += h3.x * wv; o[13] += h3.y * wv; o[14] += h3.z * wv; o[15] += h3.w * wv;
  }
  // all shfl reductions first, one sync, then finish
#pragma unroll
  for (int m = 0; m < OPN; m++) {
    float v = o[m], vv = o[m] * o[m];
#pragma unroll
    for (int off = 32; off; off >>= 1) { v += __shfl_xor(v, off); vv += __shfl_xor(vv, off); }
    if (lane == 0) { wp[m][w] = v; wq[m][w] = vv; }
  }
  __syncthreads();
  float gv = g[t], bv = beta[t];
#pragma unroll
  for (int m = 0; m < OPN; m++) {
    float mean = (wp[m][0] + wp[m][1] + wp[m][2] + wp[m][3]) * (1.f / 256.f);
    float ex2 = (wq[m][0] + wq[m][1] + wq[m][2] + wq[m][3]) * (1.f / 256.f);
    float var = ex2 - mean * mean;
    out[(n0 + m) * 256 + t] = (o[m] - mean) * rsqrtf(var + 1e-5f) * gv + bv;
  }
}

// ---------------------------------------------------------------------------
extern "C" void kernel_launch(void* const* d_in, const int* in_sizes, int n_in,
                              void* d_out, int out_size, void* d_ws, size_t ws_size,
                              hipStream_t stream) {
  const float* x         = (const float*)d_in[0];
  const float* edge_attr = (const float*)d_in[1];
  const int*   ei        = (const int*)d_in[2];
  const float* ne_w1 = (const float*)d_in[3];
  const float* ne_b1 = (const float*)d_in[4];
  const float* ne_w2 = (const float*)d_in[5];
  const float* ne_b2 = (const float*)d_in[6];
  const float* ne_g  = (const float*)d_in[7];
  const float* ne_be = (const float*)d_in[8];
  const float* ee_w1 = (const float*)d_in[9];
  const float* ee_b1 = (const float*)d_in[10];
  const float* ee_w2 = (const float*)d_in[11];
  const float* ee_b2 = (const float*)d_in[12];
  const float* ee_g  = (const float*)d_in[13];
  const float* ee_be = (const float*)d_in[14];
  const float* ra_w1 = (const float*)d_in[15];
  const float* ra_b1 = (const float*)d_in[16];
  const float* ra_w2 = (const float*)d_in[17];
  const float* ra_b2 = (const float*)d_in[18];
  const float* gat_wl  = (const float*)d_in[19];
  const float* gat_wa  = (const float*)d_in[20];
  const float* gat_we  = (const float*)d_in[21];
  const float* gat_wo  = (const float*)d_in[22];
  const float* gat_wob = (const float*)d_in[23];
  const float* ow_1 = (const float*)d_in[24];
  const float* ob_1 = (const float*)d_in[25];
  const float* ow_2 = (const float*)d_in[26];
  const float* ob_2 = (const float*)d_in[27];
  const float* o_g  = (const float*)d_in[28];
  const float* o_be = (const float*)d_in[29];
  float* out = (float*)d_out;

  char* wsb = (char*)d_ws;
  size_t off = 0;
  auto af = [&](size_t elems) -> float* { float* p = (float*)(wsb + off); off += elems * sizeof(float); return p; };
  auto ai = [&](size_t elems) -> int*   { int*   p = (int*)(wsb + off);   off += elems * sizeof(int);   return p; };

  float* h      = af((size_t)NN * 64);
  float* xh2    = af((size_t)NN * 64);
  float* efs    = af((size_t)EE * 32);   // ef rows, SORTED by destination node
  float* devs   = af((size_t)EE * 4);    // interleaved (d0,d1,d2,_) per sorted edge
  float* rws    = af((size_t)EE);        // risk weights, sorted
  float* ps     = af((size_t)EE * 4);    // per-edge softmax numerators, sorted
  float* xprojA = af((size_t)NN * 256);
  float* xprojB = af((size_t)NN * 256);  // aliased as hnode before layer 1
  float* di     = af((size_t)NN * 4);
  float* dj     = af((size_t)NN * 4);
  float* gsum   = af(12);                // 3 layers x 4 heads softmax denominators
  int* rcs    = ai(2 * (size_t)EE);      // (row, col) per sorted edge
  int* counts = ai(NN);
  int* rowptr = ai(NN + 1);
  int* cursor = ai(NN);
  float* hnode = xprojB;  // consumed by k_risk_edge before xprojB's first write
  (void)ws_size; (void)n_in; (void)in_sizes; (void)out_size;

  hipMemsetAsync(counts, 0, NN * sizeof(int), stream);
  hipMemsetAsync(gsum, 0, 12 * sizeof(float), stream);
  k_hist<<<EE / 256, 256, 0, stream>>>(ei, counts);
  k_node_enc<<<(NN + 255) / 256, 256, 0, stream>>>(x, ne_w1, ne_b1, ne_w2, ne_b2, ne_g, ne_be, h);
  k_scan<<<1, 1024, 0, stream>>>(counts, rowptr, cursor);
  k_edge_enc<<<EE / 256, 256, 0, stream>>>(edge_attr, ee_w1, ee_b1, ee_w2, ee_b2, ee_g, ee_be,
                                           gat_wa, ei, cursor, efs, (float4*)devs, (int2*)rcs);
  k_risk_node<<<NN / 16, 256, 0, stream>>>(h, ra_w1, ra_b1, hnode);
  k_risk_edge<<<EE / 256, 256, 0, stream>>>(hnode, efs, (const int2*)rcs,
                                            ra_w1 + 64 * 64, ra_w2, ra_b2, rws);
  k_xproj<<<NN / 16, 256, 0, stream>>>(h, gat_wl, gat_wa, xprojA, di, dj);

  float* xp_cur = xprojA;
  float* xp_nxt = xprojB;
  for (int l = 0; l < 3; l++) {
    const float* we  = gat_we + (size_t)l * 32 * 256;
    const float* wo  = gat_wo + (size_t)l * 64 * 64;
    const float* wob = gat_wob + (size_t)l * 64;
    float* gsum_l = gsum + l * 4;

    k_pexp<<<EE / 256, 256, 0, stream>>>((const int2*)rcs, (const float4*)devs, rws,
                                         di, dj, l, (float4*)ps, gsum_l);
    if (l < 2) {
      const float* wl_n = gat_wl + (size_t)(l + 1) * 64 * 256;
      const float* wa_n = gat_wa + (size_t)(l + 1) * 160;
      k_aggupdate<true><<<NN / 16, 256, 0, stream>>>(
          rowptr, (const float4*)ps, efs, gsum_l, xp_cur, we, wo, wob, wl_n, wa_n,
          nullptr, xp_nxt, di, dj);
      float* tmp = xp_cur; xp_cur = xp_nxt; xp_nxt = tmp;
    } else {
      k_aggupdate<false><<<NN / 16, 256, 0, stream>>>(
          rowptr, (const float4*)ps, efs, gsum_l, xp_cur, we, wo, wob, nullptr, nullptr,
          xh2, nullptr, nullptr, nullptr);
    }
  }

  k_out<<<NN / OPN, 256, 0, stream>>>(xh2, ow_1, ob_1, ow_2, ob_2, o_g, o_be, out);
}

// Round 9
// 486.598 us; speedup vs baseline: 1.3633x; 1.0914x over previous
//
#include <hip/hip_runtime.h>
#include <math.h>

#define NN 20000
#define EE 320000
#define HID 64
#define EHID 32
#define HEADS 4

__device__ __forceinline__ float fast_tanh(float x) {
  float e = __expf(2.f * x);
  return 1.f - 2.f * __builtin_amdgcn_rcpf(e + 1.f);
}
__device__ __forceinline__ float fast_sigmoid(float x) {
  return __builtin_amdgcn_rcpf(1.f + __expf(-x));
}
__device__ __forceinline__ float bcast8(float v, int q) {
  // broadcast within 8-lane group: src lane = (lane & 0b11000) | q (BitMode swizzle)
  switch (q) {
    case 0: return __int_as_float(__builtin_amdgcn_ds_swizzle(__float_as_int(v), (0 << 5) | 0x18));
    case 1: return __int_as_float(__builtin_amdgcn_ds_swizzle(__float_as_int(v), (1 << 5) | 0x18));
    case 2: return __int_as_float(__builtin_amdgcn_ds_swizzle(__float_as_int(v), (2 << 5) | 0x18));
    case 3: return __int_as_float(__builtin_amdgcn_ds_swizzle(__float_as_int(v), (3 << 5) | 0x18));
    case 4: return __int_as_float(__builtin_amdgcn_ds_swizzle(__float_as_int(v), (4 << 5) | 0x18));
    case 5: return __int_as_float(__builtin_amdgcn_ds_swizzle(__float_as_int(v), (5 << 5) | 0x18));
    case 6: return __int_as_float(__builtin_amdgcn_ds_swizzle(__float_as_int(v), (6 << 5) | 0x18));
    default: return __int_as_float(__builtin_amdgcn_ds_swizzle(__float_as_int(v), (7 << 5) | 0x18));
  }
}

// ---------------------------------------------------------------------------
// Node encoder: Linear(9,32)+ReLU+Linear(32,64)+LayerNorm(64). Thread per node.
__global__ __launch_bounds__(256) void k_node_enc(
    const float* __restrict__ x, const float* __restrict__ w1, const float* __restrict__ b1,
    const float* __restrict__ w2, const float* __restrict__ b2,
    const float* __restrict__ g, const float* __restrict__ beta,
    float* __restrict__ h) {
  int n = blockIdx.x * blockDim.x + threadIdx.x;
  if (n >= NN) return;
  float xin[9];
#pragma unroll
  for (int k = 0; k < 9; k++) xin[k] = x[n * 9 + k];
  float hid[32];
#pragma unroll
  for (int j = 0; j < 32; j++) {
    float a = b1[j];
#pragma unroll
    for (int k = 0; k < 9; k++) a += xin[k] * w1[k * 32 + j];
    hid[j] = fmaxf(a, 0.f);
  }
  float o[64];
  float s = 0.f;
  for (int j = 0; j < 64; j++) {
    float a = b2[j];
#pragma unroll
    for (int k = 0; k < 32; k++) a += hid[k] * w2[k * 64 + j];
    o[j] = a;
    s += a;
  }
  float m = s * (1.f / 64.f);
  float v = 0.f;
  for (int j = 0; j < 64; j++) { float d = o[j] - m; v += d * d; }
  v *= (1.f / 64.f);
  float inv = rsqrtf(v + 1e-5f);
#pragma unroll
  for (int j4 = 0; j4 < 16; j4++) {
    float4 r;
    r.x = (o[j4 * 4 + 0] - m) * inv * g[j4 * 4 + 0] + beta[j4 * 4 + 0];
    r.y = (o[j4 * 4 + 1] - m) * inv * g[j4 * 4 + 1] + beta[j4 * 4 + 1];
    r.z = (o[j4 * 4 + 2] - m) * inv * g[j4 * 4 + 2] + beta[j4 * 4 + 2];
    r.w = (o[j4 * 4 + 3] - m) * inv * g[j4 * 4 + 3] + beta[j4 * 4 + 3];
    ((float4*)&h[n * 64])[j4] = r;
  }
}

// ---------------------------------------------------------------------------
// CSR histogram over col
__global__ __launch_bounds__(256) void k_hist(const int* __restrict__ ei, int* __restrict__ counts) {
  int e = blockIdx.x * 256 + threadIdx.x;
  if (e < EE) atomicAdd(&counts[ei[EE + e]], 1);
}
// shfl-based single-block scan: 1024 threads x 20 elements each.
__global__ __launch_bounds__(1024) void k_scan(
    const int* __restrict__ counts, int* __restrict__ rowptr, int* __restrict__ cursor) {
  __shared__ int wsum[16];
  int t = threadIdx.x, lane = t & 63, w = t >> 6;
  const int CH = 20;  // 1024*20 >= NN
  int base_i = t * CH;
  int local = 0;
  for (int i = 0; i < CH; i++) {
    int idx = base_i + i;
    if (idx < NN) local += counts[idx];
  }
  int v = local;
#pragma unroll
  for (int off = 1; off < 64; off <<= 1) {
    int u = __shfl_up(v, off);
    if (lane >= off) v += u;
  }
  if (lane == 63) wsum[w] = v;
  __syncthreads();
  int wbase = 0;
  for (int i = 0; i < w; i++) wbase += wsum[i];
  int run = wbase + v - local;  // exclusive prefix
  for (int i = 0; i < CH; i++) {
    int idx = base_i + i;
    if (idx < NN) {
      rowptr[idx] = run;
      cursor[idx] = run;
      run += counts[idx];
    }
  }
  if (t == 1023) rowptr[NN] = EE;
}

// ---------------------------------------------------------------------------
// Edge encoder, SORTED-output: computes ef/dev, grabs CSR slot via cursor, and
// writes efs/devs4/rcs in destination-node order. Thread per edge.
__global__ __launch_bounds__(256) void k_edge_enc(
    const float* __restrict__ ea, const float* __restrict__ w1, const float* __restrict__ b1,
    const float* __restrict__ w2, const float* __restrict__ b2,
    const float* __restrict__ g, const float* __restrict__ beta,
    const float* __restrict__ gat_wa, const int* __restrict__ ei,
    int* __restrict__ cursor,
    float* __restrict__ efs, float4* __restrict__ devs4, int2* __restrict__ rcs) {
  int e = blockIdx.x * blockDim.x + threadIdx.x;
  if (e >= EE) return;
  int row = ei[e], col = ei[EE + e];
  int pos = atomicAdd(&cursor[col], 1);
  float4 xin = ((const float4*)ea)[e];
  float hid[16];
#pragma unroll
  for (int j = 0; j < 16; j++) {
    float a = b1[j];
    a += xin.x * w1[0 * 16 + j];
    a += xin.y * w1[1 * 16 + j];
    a += xin.z * w1[2 * 16 + j];
    a += xin.w * w1[3 * 16 + j];
    hid[j] = fmaxf(a, 0.f);
  }
  float o[32];
  float s = 0.f;
#pragma unroll
  for (int j = 0; j < 32; j++) {
    float a = b2[j];
#pragma unroll
    for (int k = 0; k < 16; k++) a += hid[k] * w2[k * 32 + j];
    o[j] = a;
    s += a;
  }
  float m = s * (1.f / 32.f);
  float v = 0.f;
#pragma unroll
  for (int j = 0; j < 32; j++) { float d = o[j] - m; v += d * d; }
  v *= (1.f / 32.f);
  float inv = rsqrtf(v + 1e-5f);
  float d0 = 0.f, d1 = 0.f, d2 = 0.f;
  float vn[32];
#pragma unroll
  for (int j = 0; j < 32; j++) {
    vn[j] = (o[j] - m) * inv * g[j] + beta[j];
    d0 += vn[j] * gat_wa[0 * 160 + 128 + j];
    d1 += vn[j] * gat_wa[1 * 160 + 128 + j];
    d2 += vn[j] * gat_wa[2 * 160 + 128 + j];
  }
#pragma unroll
  for (int j4 = 0; j4 < 8; j4++) {
    float4 r;
    r.x = vn[j4 * 4 + 0]; r.y = vn[j4 * 4 + 1]; r.z = vn[j4 * 4 + 2]; r.w = vn[j4 * 4 + 3];
    ((float4*)&efs[(size_t)pos * 32])[j4] = r;
  }
  devs4[pos] = make_float4(d0, d1, d2, 0.f);
  rcs[pos] = make_int2(row, col);
}

// ---------------------------------------------------------------------------
// Risk MLP part 1: hnode = h @ ra_w1[0:64,:] + b1. 16 nodes/block, transposed LDS.
__global__ __launch_bounds__(256) void k_risk_node(
    const float* __restrict__ h, const float* __restrict__ w1, const float* __restrict__ b1,
    float* __restrict__ hnode) {
  __shared__ float xsT[64][20];
  int t = threadIdx.x;
  int n0 = blockIdx.x * 16;
  const float4* h4 = (const float4*)h;
  {
    int m = t & 15, k4 = t >> 4;
    float4 xv = h4[(n0 + m) * 16 + k4];
    xsT[k4 * 4 + 0][m] = xv.x;
    xsT[k4 * 4 + 1][m] = xv.y;
    xsT[k4 * 4 + 2][m] = xv.z;
    xsT[k4 * 4 + 3][m] = xv.w;
  }
  __syncthreads();
  int j = t & 63, grp = t >> 6;
  float bv = b1[j];
  float a0 = bv, a1 = bv, a2 = bv, a3 = bv;
  for (int k = 0; k < 64; k++) {
    float wv = w1[k * 64 + j];
    float4 xv = *(const float4*)&xsT[k][grp * 4];
    a0 += xv.x * wv; a1 += xv.y * wv; a2 += xv.z * wv; a3 += xv.w * wv;
  }
  hnode[(n0 + grp * 4 + 0) * 64 + j] = a0;
  hnode[(n0 + grp * 4 + 1) * 64 + j] = a1;
  hnode[(n0 + grp * 4 + 2) * 64 + j] = a2;
  hnode[(n0 + grp * 4 + 3) * 64 + j] = a3;
}

// ---------------------------------------------------------------------------
// Risk MLP part 2, register-tiled (sorted domain): 8-lane group = 8 edges.
__global__ __launch_bounds__(256) void k_risk_edge(
    const float* __restrict__ hnode, const float* __restrict__ efs, const int2* __restrict__ rcs,
    const float* __restrict__ w1e, const float* __restrict__ w2, const float* __restrict__ b2_,
    float* __restrict__ rws) {
  int t = threadIdx.x, lane = t & 63;
  int s = lane & 7;
  int p = blockIdx.x * 256 + t;  // own sorted edge
  int myrow = rcs[p].x;
  const float4* hnode4 = (const float4*)hnode;
  const float4* efs4 = (const float4*)efs;
  const float4* w1e4 = (const float4*)w1e;
  const float4* w24 = (const float4*)w2;
  float ev[32];
#pragma unroll
  for (int i = 0; i < 8; i++) {
    float4 tmp = efs4[(size_t)p * 8 + i];
    ev[i * 4 + 0] = tmp.x; ev[i * 4 + 1] = tmp.y; ev[i * 4 + 2] = tmp.z; ev[i * 4 + 3] = tmp.w;
  }
  int rowq[8];
#pragma unroll
  for (int q = 0; q < 8; q++)
    rowq[q] = __float_as_int(bcast8(__int_as_float(myrow), q));
  float acc[8][8];
#pragma unroll
  for (int q = 0; q < 8; q++) {
    float4 ha = hnode4[(size_t)rowq[q] * 16 + s * 2];
    float4 hb = hnode4[(size_t)rowq[q] * 16 + s * 2 + 1];
    acc[q][0] = ha.x; acc[q][1] = ha.y; acc[q][2] = ha.z; acc[q][3] = ha.w;
    acc[q][4] = hb.x; acc[q][5] = hb.y; acc[q][6] = hb.z; acc[q][7] = hb.w;
  }
#pragma unroll
  for (int k = 0; k < 32; k++) {
    float4 wa4 = w1e4[k * 16 + s * 2];
    float4 wb4 = w1e4[k * 16 + s * 2 + 1];
#pragma unroll
    for (int q = 0; q < 8; q++) {
      float ekq = bcast8(ev[k], q);
      acc[q][0] += ekq * wa4.x; acc[q][1] += ekq * wa4.y;
      acc[q][2] += ekq * wa4.z; acc[q][3] += ekq * wa4.w;
      acc[q][4] += ekq * wb4.x; acc[q][5] += ekq * wb4.y;
      acc[q][6] += ekq * wb4.z; acc[q][7] += ekq * wb4.w;
    }
  }
  float4 wva = w24[s * 2], wvb = w24[s * 2 + 1];
  float tq[8];
#pragma unroll
  for (int q = 0; q < 8; q++) {
    tq[q] = fast_tanh(acc[q][0]) * wva.x + fast_tanh(acc[q][1]) * wva.y +
            fast_tanh(acc[q][2]) * wva.z + fast_tanh(acc[q][3]) * wva.w +
            fast_tanh(acc[q][4]) * wvb.x + fast_tanh(acc[q][5]) * wvb.y +
            fast_tanh(acc[q][6]) * wvb.z + fast_tanh(acc[q][7]) * wvb.w;
  }
#pragma unroll
  for (int q = 0; q < 8; q++) {
    tq[q] += __shfl_xor(tq[q], 1);
    tq[q] += __shfl_xor(tq[q], 2);
    tq[q] += __shfl_xor(tq[q], 4);
  }
  float mine = tq[0];
  mine = (s == 1) ? tq[1] : mine;
  mine = (s == 2) ? tq[2] : mine;
  mine = (s == 3) ? tq[3] : mine;
  mine = (s == 4) ? tq[4] : mine;
  mine = (s == 5) ? tq[5] : mine;
  mine = (s == 6) ? tq[6] : mine;
  mine = (s == 7) ? tq[7] : mine;
  rws[p] = fast_sigmoid(mine + b2_[0]);
}

// ---------------------------------------------------------------------------
// xproj (layer 0): wave = 4 nodes, lane = 4 cols; single bcast b128 per k-step.
__global__ __launch_bounds__(256) void k_xproj(
    const float* __restrict__ xh, const float* __restrict__ wl, const float* __restrict__ wa,
    float* __restrict__ xproj, float* __restrict__ di, float* __restrict__ dj) {
  __shared__ float xsT[64][20];
  int t = threadIdx.x, lane = t & 63, w = t >> 6;
  int n0 = blockIdx.x * 16;
  const float4* xh4 = (const float4*)xh;
  {
    int m = t & 15, k4 = t >> 4;
    float4 xv = xh4[(n0 + m) * 16 + k4];
    xsT[k4 * 4 + 0][m] = xv.x;
    xsT[k4 * 4 + 1][m] = xv.y;
    xsT[k4 * 4 + 2][m] = xv.z;
    xsT[k4 * 4 + 3][m] = xv.w;
  }
  __syncthreads();
  const float4* wl4 = (const float4*)wl;
  float4 acc0 = {0,0,0,0}, acc1 = {0,0,0,0}, acc2 = {0,0,0,0}, acc3 = {0,0,0,0};
  for (int k = 0; k < 64; k++) {
    float4 xv = *(const float4*)&xsT[k][4 * w];       // uniform broadcast
    float4 wv = wl4[k * 64 + lane];                   // wl[k][4c..4c+3]
    acc0.x += xv.x * wv.x; acc0.y += xv.x * wv.y; acc0.z += xv.x * wv.z; acc0.w += xv.x * wv.w;
    acc1.x += xv.y * wv.x; acc1.y += xv.y * wv.y; acc1.z += xv.y * wv.z; acc1.w += xv.y * wv.w;
    acc2.x += xv.z * wv.x; acc2.y += xv.z * wv.y; acc2.z += xv.z * wv.z; acc2.w += xv.z * wv.w;
    acc3.x += xv.w * wv.x; acc3.y += xv.w * wv.y; acc3.z += xv.w * wv.z; acc3.w += xv.w * wv.w;
  }
  float4* xp4 = (float4*)xproj;
  xp4[(size_t)(n0 + 4 * w + 0) * 64 + lane] = acc0;
  xp4[(size_t)(n0 + 4 * w + 1) * 64 + lane] = acc1;
  xp4[(size_t)(n0 + 4 * w + 2) * 64 + lane] = acc2;
  xp4[(size_t)(n0 + 4 * w + 3) * 64 + lane] = acc3;
  // di/dj: cols 4c..4c+3 all in head c>>4; reduce over 16-lane groups.
  float4 wi4 = ((const float4*)wa)[lane];
  float4 wj4 = ((const float4*)wa)[16 + lane];
  float4 accq[4] = {acc0, acc1, acc2, acc3};
#pragma unroll
  for (int q = 0; q < 4; q++) {
    float vi = accq[q].x * wi4.x + accq[q].y * wi4.y + accq[q].z * wi4.z + accq[q].w * wi4.w;
    float vj = accq[q].x * wj4.x + accq[q].y * wj4.y + accq[q].z * wj4.z + accq[q].w * wj4.w;
#pragma unroll
    for (int off = 1; off < 16; off <<= 1) { vi += __shfl_xor(vi, off); vj += __shfl_xor(vj, off); }
    if ((lane & 15) == 0) {
      di[(n0 + 4 * w + q) * 4 + (lane >> 4)] = vi;
      dj[(n0 + 4 * w + q) * 4 + (lane >> 4)] = vj;
    }
  }
}

// ---------------------------------------------------------------------------
// Edge-parallel p computation: ps[i] = exp(leaky(di[r]+dj[c]+dev)*rw), once per
// edge; accumulates global softmax denominator via block-reduced atomics.
__global__ __launch_bounds__(256) void k_pexp(
    const int2* __restrict__ rcs, const float4* __restrict__ devs4,
    const float* __restrict__ rws, const float* __restrict__ di,
    const float* __restrict__ dj, int layer,
    float4* __restrict__ ps4, float* __restrict__ gsum_l) {
  __shared__ float wred[4][4];
  int t = threadIdx.x, lane = t & 63, w = t >> 6;
  int i = blockIdx.x * 256 + t;  // EE % 256 == 0
  int2 rc = rcs[i];
  float4 dv = devs4[i];
  float dev = (layer == 0) ? dv.x : ((layer == 1) ? dv.y : dv.z);
  float rv = rws[i];
  float4 dr = ((const float4*)di)[rc.x];
  float4 djc = ((const float4*)dj)[rc.y];
  float z0 = dr.x + djc.x + dev, z1 = dr.y + djc.y + dev;
  float z2 = dr.z + djc.z + dev, z3 = dr.w + djc.w + dev;
  z0 = ((z0 >= 0.f) ? z0 : 0.2f * z0) * rv;
  z1 = ((z1 >= 0.f) ? z1 : 0.2f * z1) * rv;
  z2 = ((z2 >= 0.f) ? z2 : 0.2f * z2) * rv;
  z3 = ((z3 >= 0.f) ? z3 : 0.2f * z3) * rv;
  float4 pv;
  pv.x = __expf(z0); pv.y = __expf(z1); pv.z = __expf(z2); pv.w = __expf(z3);
  ps4[i] = pv;
  float sh[4] = {pv.x, pv.y, pv.z, pv.w};
#pragma unroll
  for (int h = 0; h < 4; h++) {
    float v = sh[h];
#pragma unroll
    for (int off = 32; off; off >>= 1) v += __shfl_xor(v, off);
    if (lane == 0) wred[w][h] = v;
  }
  __syncthreads();
  if (t < 4) atomicAdd(&gsum_l[t], wred[0][t] + wred[1][t] + wred[2][t] + wred[3][t]);
}

// ---------------------------------------------------------------------------
// FUSED aggregation + node update (+ next-layer xproj + di/dj).
template <bool DO_XPROJ>
__global__ __launch_bounds__(256) void k_aggupdate(
    const int* __restrict__ rowptr, const float4* __restrict__ ps4,
    const float* __restrict__ efs, const float* __restrict__ gsum_l,
    const float* __restrict__ xproj,
    const float* __restrict__ we, const float* __restrict__ wo, const float* __restrict__ wob,
    const float* __restrict__ wl_next, const float* __restrict__ wa_next,
    float* __restrict__ xh_out, float* __restrict__ xproj_out,
    float* __restrict__ di, float* __restrict__ dj) {
  __shared__ float tsT[128][20];
  __shared__ float usT[64][20];
  __shared__ float xhT[64][20];
  __shared__ float ss[16][4];
  int t = threadIdx.x, lane = t & 63, wv = t >> 6;
  int n0 = blockIdx.x * 16;
  float4 gs = *((const float4*)gsum_l);
  float inv0 = 1.0f / gs.x, inv1 = 1.0f / gs.y, inv2 = 1.0f / gs.z, inv3 = 1.0f / gs.w;
  int c = lane & 31, slot = lane >> 5;
  // ---- aggregation phase: 4 nodes per wave, streaming sorted edges ----
#pragma unroll
  for (int q = 0; q < 4; q++) {
    int n = n0 + wv * 4 + q;
    int beg = rowptr[n], end = rowptr[n + 1];
    float a0 = 0.f, a1 = 0.f, a2 = 0.f, a3 = 0.f;
    float s0 = 0.f, s1 = 0.f, s2 = 0.f, s3 = 0.f;
    int i = beg + slot;
    for (; i + 2 < end; i += 4) {
      float4 pa = ps4[i];
      float eva = efs[(size_t)i * 32 + c];
      float4 pb = ps4[i + 2];
      float evb = efs[(size_t)(i + 2) * 32 + c];
      a0 += pa.x * eva + pb.x * evb;
      a1 += pa.y * eva + pb.y * evb;
      a2 += pa.z * eva + pb.z * evb;
      a3 += pa.w * eva + pb.w * evb;
      s0 += pa.x + pb.x; s1 += pa.y + pb.y;
      s2 += pa.z + pb.z; s3 += pa.w + pb.w;
    }
    if (i < end) {
      float4 pa = ps4[i];
      float eva = efs[(size_t)i * 32 + c];
      a0 += pa.x * eva; a1 += pa.y * eva; a2 += pa.z * eva; a3 += pa.w * eva;
      s0 += pa.x; s1 += pa.y; s2 += pa.z; s3 += pa.w;
    }
    a0 += __shfl_xor(a0, 32); a1 += __shfl_xor(a1, 32);
    a2 += __shfl_xor(a2, 32); a3 += __shfl_xor(a3, 32);
    s0 += __shfl_xor(s0, 32); s1 += __shfl_xor(s1, 32);
    s2 += __shfl_xor(s2, 32); s3 += __shfl_xor(s3, 32);
    if (slot == 0) {
      int m = wv * 4 + q;
      tsT[0 * 32 + c][m] = a0 * inv0;
      tsT[1 * 32 + c][m] = a1 * inv1;
      tsT[2 * 32 + c][m] = a2 * inv2;
      tsT[3 * 32 + c][m] = a3 * inv3;
      if (c < 4) {
        float sv = (c == 0) ? s0 : (c == 1) ? s1 : (c == 2) ? s2 : s3;
        float iv = (c == 0) ? inv0 : (c == 1) ? inv1 : (c == 2) ? inv2 : inv3;
        ss[m][c] = sv * iv;
      }
    }
  }
  __syncthreads();
  // ---- update phase ----
  int j = lane, grp = wv;
  float u0 = 0.f, u1 = 0.f, u2 = 0.f, u3 = 0.f;
#pragma unroll
  for (int h = 0; h < 4; h++) {
    u0 += xproj[(n0 + grp * 4 + 0) * 256 + h * 64 + j] * ss[grp * 4 + 0][h];
    u1 += xproj[(n0 + grp * 4 + 1) * 256 + h * 64 + j] * ss[grp * 4 + 1][h];
    u2 += xproj[(n0 + grp * 4 + 2) * 256 + h * 64 + j] * ss[grp * 4 + 2][h];
    u3 += xproj[(n0 + grp * 4 + 3) * 256 + h * 64 + j] * ss[grp * 4 + 3][h];
  }
  for (int hc = 0; hc < 128; hc++) {
    float wv2 = we[(hc & 31) * 256 + (hc >> 5) * 64 + j];
    float4 tv = *(const float4*)&tsT[hc][grp * 4];
    u0 += tv.x * wv2; u1 += tv.y * wv2; u2 += tv.z * wv2; u3 += tv.w * wv2;
  }
  *(float4*)&usT[j][grp * 4] = make_float4(u0 * 0.25f, u1 * 0.25f, u2 * 0.25f, u3 * 0.25f);
  __syncthreads();
  float ob = wob[j];
  float o0 = ob, o1 = ob, o2 = ob, o3 = ob;
  for (int k = 0; k < 64; k++) {
    float wv2 = wo[k * 64 + j];
    float4 uv = *(const float4*)&usT[k][grp * 4];
    o0 += uv.x * wv2; o1 += uv.y * wv2; o2 += uv.z * wv2; o3 += uv.w * wv2;
  }
  o0 = fmaxf(o0, 0.f); o1 = fmaxf(o1, 0.f); o2 = fmaxf(o2, 0.f); o3 = fmaxf(o3, 0.f);
  if (!DO_XPROJ) {
    xh_out[(n0 + grp * 4 + 0) * 64 + j] = o0;
    xh_out[(n0 + grp * 4 + 1) * 64 + j] = o1;
    xh_out[(n0 + grp * 4 + 2) * 64 + j] = o2;
    xh_out[(n0 + grp * 4 + 3) * 64 + j] = o3;
    return;
  }
  xhT[j][grp * 4 + 0] = o0;
  xhT[j][grp * 4 + 1] = o1;
  xhT[j][grp * 4 + 2] = o2;
  xhT[j][grp * 4 + 3] = o3;
  __syncthreads();
  // ---- next-layer xproj: wave = 4 nodes, lane = 4 cols, bcast b128 per k ----
  const float4* wl4 = (const float4*)wl_next;
  float4 acc0 = {0,0,0,0}, acc1 = {0,0,0,0}, acc2 = {0,0,0,0}, acc3 = {0,0,0,0};
  for (int k = 0; k < 64; k++) {
    float4 xv = *(const float4*)&xhT[k][4 * wv];      // uniform broadcast
    float4 wv2 = wl4[k * 64 + lane];
    acc0.x += xv.x * wv2.x; acc0.y += xv.x * wv2.y; acc0.z += xv.x * wv2.z; acc0.w += xv.x * wv2.w;
    acc1.x += xv.y * wv2.x; acc1.y += xv.y * wv2.y; acc1.z += xv.y * wv2.z; acc1.w += xv.y * wv2.w;
    acc2.x += xv.z * wv2.x; acc2.y += xv.z * wv2.y; acc2.z += xv.z * wv2.z; acc2.w += xv.z * wv2.w;
    acc3.x += xv.w * wv2.x; acc3.y += xv.w * wv2.y; acc3.z += xv.w * wv2.z; acc3.w += xv.w * wv2.w;
  }
  float4* xp4 = (float4*)xproj_out;
  xp4[(size_t)(n0 + 4 * wv + 0) * 64 + lane] = acc0;
  xp4[(size_t)(n0 + 4 * wv + 1) * 64 + lane] = acc1;
  xp4[(size_t)(n0 + 4 * wv + 2) * 64 + lane] = acc2;
  xp4[(size_t)(n0 + 4 * wv + 3) * 64 + lane] = acc3;
  float4 wi4 = ((const float4*)wa_next)[lane];
  float4 wj4 = ((const float4*)wa_next)[16 + lane];
  float4 accq[4] = {acc0, acc1, acc2, acc3};
#pragma unroll
  for (int q = 0; q < 4; q++) {
    float vi = accq[q].x * wi4.x + accq[q].y * wi4.y + accq[q].z * wi4.z + accq[q].w * wi4.w;
    float vj = accq[q].x * wj4.x + accq[q].y * wj4.y + accq[q].z * wj4.z + accq[q].w * wj4.w;
#pragma unroll
    for (int off = 1; off < 16; off <<= 1) { vi += __shfl_xor(vi, off); vj += __shfl_xor(vj, off); }
    if ((lane & 15) == 0) {
      di[(n0 + 4 * wv + q) * 4 + (lane >> 4)] = vi;
      dj[(n0 + 4 * wv + q) * 4 + (lane >> 4)] = vj;
    }
  }
}

// ---------------------------------------------------------------------------
// Output layer: Linear(64,128)+ReLU+Linear(128,256)+LayerNorm(256).
// 16 nodes/block; wave = 4 nodes, lane = 4 cols; 1 bcast b128 per k-step;
// LayerNorm fully in-wave (node's 256 cols live in one wave).
#define OPN 16
__global__ __launch_bounds__(256) void k_out(
    const float* __restrict__ xh, const float* __restrict__ w1, const float* __restrict__ b1,
    const float* __restrict__ w2, const float* __restrict__ b2,
    const float* __restrict__ g, const float* __restrict__ beta,
    float* __restrict__ out) {
  __shared__ float xsT[64][20];
  __shared__ float hsT[128][20];
  int t = threadIdx.x, lane = t & 63, w = t >> 6;
  int n0 = blockIdx.x * OPN;
  const float4* xh4 = (const float4*)xh;
  {
    int m = t & 15, k4 = t >> 4;  // 256 threads = 256 float4s
    float4 xv = xh4[(n0 + m) * 16 + k4];
    xsT[k4 * 4 + 0][m] = xv.x;
    xsT[k4 * 4 + 1][m] = xv.y;
    xsT[k4 * 4 + 2][m] = xv.z;
    xsT[k4 * 4 + 3][m] = xv.w;
  }
  __syncthreads();
  // stage 1: hidden = relu(xh@w1+b1); wave w = nodes 4w..4w+3; lane owns
  // hidden cols {lane, lane+64}.
  {
    float b0 = b1[lane], b64 = b1[64 + lane];
    float4 h0 = make_float4(b0, b0, b0, b0);
    float4 h1 = make_float4(b64, b64, b64, b64);
    for (int k = 0; k < 64; k++) {
      float4 xv = *(const float4*)&xsT[k][4 * w];     // uniform broadcast
      float wa = w1[k * 128 + lane];
      float wb = w1[k * 128 + 64 + lane];
      h0.x += xv.x * wa; h0.y += xv.y * wa; h0.z += xv.z * wa; h0.w += xv.w * wa;
      h1.x += xv.x * wb; h1.y += xv.y * wb; h1.z += xv.z * wb; h1.w += xv.w * wb;
    }
    h0.x = fmaxf(h0.x, 0.f); h0.y = fmaxf(h0.y, 0.f); h0.z = fmaxf(h0.z, 0.f); h0.w = fmaxf(h0.w, 0.f);
    h1.x = fmaxf(h1.x, 0.f); h1.y = fmaxf(h1.y, 0.f); h1.z = fmaxf(h1.z, 0.f); h1.w = fmaxf(h1.w, 0.f);
    *(float4*)&hsT[lane][4 * w] = h0;
    *(float4*)&hsT[64 + lane][4 * w] = h1;
  }
  __syncthreads();
  // stage 2: out = hs@w2+b2; lane owns out cols 4*lane..4*lane+3.
  const float4* w24 = (const float4*)w2;
  float4 b2v = ((const float4*)b2)[lane];
  float4 o0 = b2v, o1 = b2v, o2 = b2v, o3 = b2v;
  for (int k = 0; k < 128; k++) {
    float4 hv = *(const float4*)&hsT[k][4 * w];       // uniform broadcast
    float4 wv = w24[k * 64 + lane];
    o0.x += hv.x * wv.x; o0.y += hv.x * wv.y; o0.z += hv.x * wv.z; o0.w += hv.x * wv.w;
    o1.x += hv.y * wv.x; o1.y += hv.y * wv.y; o1.z += hv.y * wv.z; o1.w += hv.y * wv.w;
    o2.x += hv.z * wv.x; o2.y += hv.z * wv.y; o2.z += hv.z * wv.z; o2.w += hv.z * wv.w;
    o3.x += hv.w * wv.x; o3.y += hv.w * wv.y; o3.z += hv.w * wv.z; o3.w += hv.w * wv.w;
  }
  // LayerNorm per node, fully in-wave.
  float4 gv = ((const float4*)g)[lane];
  float4 bv = ((const float4*)beta)[lane];
  float4* out4 = (float4*)out;
  float4 oq[4] = {o0, o1, o2, o3};
#pragma unroll
  for (int q = 0; q < 4; q++) {
    float s1 = oq[q].x + oq[q].y + oq[q].z + oq[q].w;
    float s2 = oq[q].x * oq[q].x + oq[q].y * oq[q].y + oq[q].z * oq[q].z + oq[q].w * oq[q].w;
#pragma unroll
    for (int off = 1; off < 64; off <<= 1) { s1 += __shfl_xor(s1, off); s2 += __shfl_xor(s2, off); }
    float mean = s1 * (1.f / 256.f);
    float var = s2 * (1.f / 256.f) - mean * mean;
    float inv = rsqrtf(var + 1e-5f);
    float4 r;
    r.x = (oq[q].x - mean) * inv * gv.x + bv.x;
    r.y = (oq[q].y - mean) * inv * gv.y + bv.y;
    r.z = (oq[q].z - mean) * inv * gv.z + bv.z;
    r.w = (oq[q].w - mean) * inv * gv.w + bv.w;
    out4[(size_t)(n0 + 4 * w + q) * 64 + lane] = r;
  }
}

// ---------------------------------------------------------------------------
extern "C" void kernel_launch(void* const* d_in, const int* in_sizes, int n_in,
                              void* d_out, int out_size, void* d_ws, size_t ws_size,
                              hipStream_t stream) {
  const float* x         = (const float*)d_in[0];
  const float* edge_attr = (const float*)d_in[1];
  const int*   ei        = (const int*)d_in[2];
  const float* ne_w1 = (const float*)d_in[3];
  const float* ne_b1 = (const float*)d_in[4];
  const float* ne_w2 = (const float*)d_in[5];
  const float* ne_b2 = (const float*)d_in[6];
  const float* ne_g  = (const float*)d_in[7];
  const float* ne_be = (const float*)d_in[8];
  const float* ee_w1 = (const float*)d_in[9];
  const float* ee_b1 = (const float*)d_in[10];
  const float* ee_w2 = (const float*)d_in[11];
  const float* ee_b2 = (const float*)d_in[12];
  const float* ee_g  = (const float*)d_in[13];
  const float* ee_be = (const float*)d_in[14];
  const float* ra_w1 = (const float*)d_in[15];
  const float* ra_b1 = (const float*)d_in[16];
  const float* ra_w2 = (const float*)d_in[17];
  const float* ra_b2 = (const float*)d_in[18];
  const float* gat_wl  = (const float*)d_in[19];
  const float* gat_wa  = (const float*)d_in[20];
  const float* gat_we  = (const float*)d_in[21];
  const float* gat_wo  = (const float*)d_in[22];
  const float* gat_wob = (const float*)d_in[23];
  const float* ow_1 = (const float*)d_in[24];
  const float* ob_1 = (const float*)d_in[25];
  const float* ow_2 = (const float*)d_in[26];
  const float* ob_2 = (const float*)d_in[27];
  const float* o_g  = (const float*)d_in[28];
  const float* o_be = (const float*)d_in[29];
  float* out = (float*)d_out;

  char* wsb = (char*)d_ws;
  size_t off = 0;
  auto af = [&](size_t elems) -> float* { float* p = (float*)(wsb + off); off += elems * sizeof(float); return p; };
  auto ai = [&](size_t elems) -> int*   { int*   p = (int*)(wsb + off);   off += elems * sizeof(int);   return p; };

  float* h      = af((size_t)NN * 64);
  float* xh2    = af((size_t)NN * 64);
  float* efs    = af((size_t)EE * 32);   // ef rows, SORTED by destination node
  float* devs   = af((size_t)EE * 4);    // interleaved (d0,d1,d2,_) per sorted edge
  float* rws    = af((size_t)EE);        // risk weights, sorted
  float* ps     = af((size_t)EE * 4);    // per-edge softmax numerators, sorted
  float* xprojA = af((size_t)NN * 256);
  float* xprojB = af((size_t)NN * 256);  // aliased as hnode before layer 1
  float* di     = af((size_t)NN * 4);
  float* dj     = af((size_t)NN * 4);
  float* gsum   = af(12);                // 3 layers x 4 heads softmax denominators
  int* rcs    = ai(2 * (size_t)EE);      // (row, col) per sorted edge
  int* counts = ai(NN);
  int* rowptr = ai(NN + 1);
  int* cursor = ai(NN);
  float* hnode = xprojB;  // consumed by k_risk_edge before xprojB's first write
  (void)ws_size; (void)n_in; (void)in_sizes; (void)out_size;

  hipMemsetAsync(counts, 0, NN * sizeof(int), stream);
  hipMemsetAsync(gsum, 0, 12 * sizeof(float), stream);
  k_hist<<<EE / 256, 256, 0, stream>>>(ei, counts);
  k_node_enc<<<(NN + 255) / 256, 256, 0, stream>>>(x, ne_w1, ne_b1, ne_w2, ne_b2, ne_g, ne_be, h);
  k_scan<<<1, 1024, 0, stream>>>(counts, rowptr, cursor);
  k_edge_enc<<<EE / 256, 256, 0, stream>>>(edge_attr, ee_w1, ee_b1, ee_w2, ee_b2, ee_g, ee_be,
                                           gat_wa, ei, cursor, efs, (float4*)devs, (int2*)rcs);
  k_risk_node<<<NN / 16, 256, 0, stream>>>(h, ra_w1, ra_b1, hnode);
  k_risk_edge<<<EE / 256, 256, 0, stream>>>(hnode, efs, (const int2*)rcs,
                                            ra_w1 + 64 * 64, ra_w2, ra_b2, rws);
  k_xproj<<<NN / 16, 256, 0, stream>>>(h, gat_wl, gat_wa, xprojA, di, dj);

  float* xp_cur = xprojA;
  float* xp_nxt = xprojB;
  for (int l = 0; l < 3; l++) {
    const float* we  = gat_we + (size_t)l * 32 * 256;
    const float* wo  = gat_wo + (size_t)l * 64 * 64;
    const float* wob = gat_wob + (size_t)l * 64;
    float* gsum_l = gsum + l * 4;

    k_pexp<<<EE / 256, 256, 0, stream>>>((const int2*)rcs, (const float4*)devs, rws,
                                         di, dj, l, (float4*)ps, gsum_l);
    if (l < 2) {
      const float* wl_n = gat_wl + (size_t)(l + 1) * 64 * 256;
      const float* wa_n = gat_wa + (size_t)(l + 1) * 160;
      k_aggupdate<true><<<NN / 16, 256, 0, stream>>>(
          rowptr, (const float4*)ps, efs, gsum_l, xp_cur, we, wo, wob, wl_n, wa_n,
          nullptr, xp_nxt, di, dj);
      float* tmp = xp_cur; xp_cur = xp_nxt; xp_nxt = tmp;
    } else {
      k_aggupdate<false><<<NN / 16, 256, 0, stream>>>(
          rowptr, (const float4*)ps, efs, gsum_l, xp_cur, we, wo, wob, nullptr, nullptr,
          xh2, nullptr, nullptr, nullptr);
    }
  }

  k_out<<<NN / OPN, 256, 0, stream>>>(xh2, ow_1, ob_1, ow_2, ob_2, o_g, o_be, out);
}